// Round 1
// baseline (509.846 us; speedup 1.0000x reference)
//
#include <hip/hip_runtime.h>

#define NN 100000
#define NE 1600000
#define DIM 64

// ---------------- degree / normalization ----------------

__global__ void k_init_deg(float* __restrict__ deg, int n) {
    int i = blockIdx.x * blockDim.x + threadIdx.x;
    if (i < n) deg[i] = 1.0f;  // self-loop
}

__global__ void k_count(const int* __restrict__ ei, float* __restrict__ deg, int E) {
    int e = blockIdx.x * blockDim.x + threadIdx.x;
    if (e < E) atomicAdd(&deg[ei[E + e]], 1.0f);  // dst = ei[1][e]
}

__global__ void k_dinv(float* __restrict__ deg, int n) {
    int i = blockIdx.x * blockDim.x + threadIdx.x;
    if (i < n) deg[i] = rsqrtf(deg[i]);  // deg >= 1 always
}

// ---------------- fused dense: h = xW ; out = xW_lin + b + b_lin + dinv^2*h ----------------

__global__ __launch_bounds__(256) void k_gemm(
    const float* __restrict__ x, const float* __restrict__ W,
    const float* __restrict__ b, const float* __restrict__ Wl,
    const float* __restrict__ bl, const float* __restrict__ dinv,
    float* __restrict__ h, float* __restrict__ out, int n) {
    __shared__ float Ws[DIM * DIM];
    __shared__ float Wls[DIM * DIM];
    __shared__ float xs[4][DIM];

    for (int i = threadIdx.x; i < DIM * DIM; i += 256) {
        Ws[i]  = W[i];
        Wls[i] = Wl[i];
    }

    const int r = threadIdx.x >> 6;   // row within 4-row tile
    const int c = threadIdx.x & 63;   // output column
    const float bc = b[c] + bl[c];

    const int ntiles = (n + 3) >> 2;
    for (int tile = blockIdx.x; tile < ntiles; tile += gridDim.x) {
        const int row0 = tile * 4;
        __syncthreads();  // xs free to overwrite
        {
            int row = row0 + r;
            xs[r][c] = (row < n) ? x[row * DIM + c] : 0.0f;
        }
        __syncthreads();
        int row = row0 + r;
        if (row < n) {
            float acc = bc, accW = 0.0f;
#pragma unroll
            for (int k = 0; k < DIM; ++k) {
                float xv = xs[r][k];               // LDS broadcast
                accW += xv * Ws[k * DIM + c];      // stride-1 across lanes
                acc  += xv * Wls[k * DIM + c];
            }
            float dv = dinv[row];
            h[row * DIM + c]   = accW;
            out[row * DIM + c] = acc + dv * dv * accW;  // self-loop folded in
        }
    }
}

// ---------------- edge scatter: out[dst] += h[src] * dinv[src]*dinv[dst] ----------------

__global__ __launch_bounds__(256) void k_scatter(
    const int* __restrict__ ei, const float* __restrict__ h,
    const float* __restrict__ dinv, float* __restrict__ out, int E) {
    int t = blockIdx.x * blockDim.x + threadIdx.x;
    int e = t >> 6;
    if (e >= E) return;
    int c = t & 63;
    int src = ei[e];
    int dst = ei[E + e];
    float norm = dinv[src] * dinv[dst];
    atomicAdd(&out[dst * DIM + c], h[src * DIM + c] * norm);
}

// ---------------- launch ----------------

extern "C" void kernel_launch(void* const* d_in, const int* in_sizes, int n_in,
                              void* d_out, int out_size, void* d_ws, size_t ws_size,
                              hipStream_t stream) {
    const float* x  = (const float*)d_in[0];
    const int*   ei = (const int*)d_in[1];   // [2, E] int32 (JAX x64-disabled)
    const float* W  = (const float*)d_in[2];
    const float* b  = (const float*)d_in[3];
    const float* Wl = (const float*)d_in[4];
    const float* bl = (const float*)d_in[5];
    float* out = (float*)d_out;

    float* deg = (float*)d_ws;                             // NN floats (becomes dinv)
    float* h   = (float*)((char*)d_ws + (512 * 1024));     // NN*DIM floats

    k_init_deg<<<(NN + 255) / 256, 256, 0, stream>>>(deg, NN);
    k_count<<<(NE + 255) / 256, 256, 0, stream>>>(ei, deg, NE);
    k_dinv<<<(NN + 255) / 256, 256, 0, stream>>>(deg, NN);
    k_gemm<<<2048, 256, 0, stream>>>(x, W, b, Wl, bl, deg, h, out, NN);

    long long total = (long long)NE * DIM;
    int nblk = (int)((total + 255) / 256);
    k_scatter<<<nblk, 256, 0, stream>>>(ei, h, deg, out, NE);
}

// Round 2
// 450.415 us; speedup vs baseline: 1.1319x; 1.1319x over previous
//
#include <hip/hip_runtime.h>

#define NN 100000
#define NE 1600000
#define DIM 64
#define NB 391          // ceil(NN/256)

// ---------------- histogram ----------------

__global__ void k_zero(int* __restrict__ cnt, int n) {
    int i = blockIdx.x * blockDim.x + threadIdx.x;
    if (i < n) cnt[i] = 0;
}

__global__ void k_count(const int* __restrict__ ei, int* __restrict__ cnt, int E) {
    int e = blockIdx.x * blockDim.x + threadIdx.x;
    if (e < E) atomicAdd(&cnt[ei[E + e]], 1);  // dst = ei[1][e]
}

// ---------------- exclusive scan (3 kernels) ----------------

__global__ __launch_bounds__(256) void k_scan1(const int* __restrict__ cnt,
                                               int* __restrict__ pre,   // per-elem excl-within-block
                                               int* __restrict__ bsum, int n) {
    __shared__ int s[256];
    int t = threadIdx.x;
    int i = blockIdx.x * 256 + t;
    int v = (i < n) ? cnt[i] : 0;
    s[t] = v; __syncthreads();
    for (int off = 1; off < 256; off <<= 1) {
        int a = (t >= off) ? s[t - off] : 0;
        __syncthreads();
        s[t] += a;
        __syncthreads();
    }
    if (i < n) pre[i] = s[t] - v;          // exclusive within block
    if (t == 255) bsum[blockIdx.x] = s[255];
}

__global__ __launch_bounds__(512) void k_scan2(int* __restrict__ bsum,
                                               int* __restrict__ boff, int nb) {
    __shared__ int s[512];
    int t = threadIdx.x;
    int v = (t < nb) ? bsum[t] : 0;
    s[t] = v; __syncthreads();
    for (int off = 1; off < 512; off <<= 1) {
        int a = (t >= off) ? s[t - off] : 0;
        __syncthreads();
        s[t] += a;
        __syncthreads();
    }
    if (t < nb) boff[t] = s[t] - v;        // exclusive block offsets
}

__global__ __launch_bounds__(256) void k_scan3(const int* __restrict__ cnt,
                                               int* __restrict__ pre,      // in: excl-within-block, out: rowptr
                                               const int* __restrict__ boff,
                                               int* __restrict__ cursor,
                                               float* __restrict__ dinv, int n) {
    int i = blockIdx.x * 256 + threadIdx.x;
    if (i < n) {
        int r = pre[i] + boff[blockIdx.x];
        pre[i] = r;                         // rowptr (exclusive)
        cursor[i] = r;
        dinv[i] = rsqrtf((float)(cnt[i] + 1));  // +1 self-loop
    }
}

// ---------------- CSR fill ----------------

__global__ void k_fill(const int* __restrict__ ei, int* __restrict__ cursor,
                       int* __restrict__ csr_src, int E) {
    int e = blockIdx.x * blockDim.x + threadIdx.x;
    if (e < E) {
        int src = ei[e];
        int dst = ei[E + e];
        int pos = atomicAdd(&cursor[dst], 1);
        csr_src[pos] = src;
    }
}

// ---------------- fused dense: g = (xW)*dinv ; out = xW_lin + b + b_lin + dinv*g ----------------

__global__ __launch_bounds__(256) void k_gemm(
    const float* __restrict__ x, const float* __restrict__ W,
    const float* __restrict__ b, const float* __restrict__ Wl,
    const float* __restrict__ bl, const float* __restrict__ dinv,
    float* __restrict__ g, float* __restrict__ out, int n) {
    __shared__ float Ws[DIM * DIM];
    __shared__ float Wls[DIM * DIM];
    __shared__ float xs[4][DIM];

    for (int i = threadIdx.x; i < DIM * DIM; i += 256) {
        Ws[i]  = W[i];
        Wls[i] = Wl[i];
    }

    const int r = threadIdx.x >> 6;
    const int c = threadIdx.x & 63;
    const float bc = b[c] + bl[c];

    const int ntiles = (n + 3) >> 2;
    for (int tile = blockIdx.x; tile < ntiles; tile += gridDim.x) {
        const int row0 = tile * 4;
        __syncthreads();
        {
            int row = row0 + r;
            xs[r][c] = (row < n) ? x[row * DIM + c] : 0.0f;
        }
        __syncthreads();
        int row = row0 + r;
        if (row < n) {
            float acc = bc, accW = 0.0f;
#pragma unroll
            for (int k = 0; k < DIM; ++k) {
                float xv = xs[r][k];
                accW += xv * Ws[k * DIM + c];
                acc  += xv * Wls[k * DIM + c];
            }
            float dv = dinv[row];
            float gv = accW * dv;            // fold dinv[src] into message
            g[row * DIM + c]   = gv;
            out[row * DIM + c] = acc + dv * gv;  // self-loop term
        }
    }
}

// ---------------- gather: out[i] += dinv[i] * sum_j g[csr_src[j]] ----------------

__global__ __launch_bounds__(256) void k_gather(
    const int* __restrict__ rowptr, const int* __restrict__ cnt,
    const int* __restrict__ csr_src, const float* __restrict__ g,
    const float* __restrict__ dinv, float* __restrict__ out, int n) {
    int wid = blockIdx.x * 4 + (threadIdx.x >> 6);   // node id (1 wave per node)
    if (wid >= n) return;
    int lane = threadIdx.x & 63;
    int start = rowptr[wid];
    int m = cnt[wid];
    float acc = 0.0f;
    for (int j = 0; j < m; ++j) {
        int s = csr_src[start + j];                  // wave-uniform broadcast load
        acc += g[s * DIM + lane];                    // coalesced 256B row gather (L3-hit)
    }
    out[wid * DIM + lane] += dinv[wid] * acc;
}

// ---------------- launch ----------------

extern "C" void kernel_launch(void* const* d_in, const int* in_sizes, int n_in,
                              void* d_out, int out_size, void* d_ws, size_t ws_size,
                              hipStream_t stream) {
    const float* x  = (const float*)d_in[0];
    const int*   ei = (const int*)d_in[1];
    const float* W  = (const float*)d_in[2];
    const float* b  = (const float*)d_in[3];
    const float* Wl = (const float*)d_in[4];
    const float* bl = (const float*)d_in[5];
    float* out = (float*)d_out;

    char* ws = (char*)d_ws;
    int*   cnt     = (int*)(ws + 0);             // 400000 B
    int*   rowptr  = (int*)(ws + 400000);        // 400000 B (pre -> rowptr in place)
    int*   cursor  = (int*)(ws + 800000);        // 400000 B
    float* dinv    = (float*)(ws + 1200000);     // 400000 B
    int*   bsum    = (int*)(ws + 1600000);       // 4096 B
    int*   boff    = (int*)(ws + 1604096);       // 4096 B
    int*   csr_src = (int*)(ws + 1608192);       // 6400000 B
    float* g       = (float*)(ws + 8008192);     // 25600000 B

    k_zero <<<NB, 256, 0, stream>>>(cnt, NN);
    k_count<<<(NE + 255) / 256, 256, 0, stream>>>(ei, cnt, NE);
    k_scan1<<<NB, 256, 0, stream>>>(cnt, rowptr, bsum, NN);
    k_scan2<<<1, 512, 0, stream>>>(bsum, boff, NB);
    k_scan3<<<NB, 256, 0, stream>>>(cnt, rowptr, boff, cursor, dinv, NN);
    k_fill <<<(NE + 255) / 256, 256, 0, stream>>>(ei, cursor, csr_src, NE);
    k_gemm <<<2048, 256, 0, stream>>>(x, W, b, Wl, bl, dinv, g, out, NN);
    k_gather<<<(NN + 3) / 4, 256, 0, stream>>>(rowptr, cnt, csr_src, g, dinv, out, NN);
}

// Round 3
// 332.823 us; speedup vs baseline: 1.5319x; 1.3533x over previous
//
#include <hip/hip_runtime.h>

#define NN 100000
#define NE 1600000
#define DIM 64
#define NB 391          // ceil(NN/256)

__device__ __forceinline__ unsigned short f2bf(float f) {
    union { float f; unsigned u; } c; c.f = f;
    unsigned r = (c.u + 0x7FFFu + ((c.u >> 16) & 1u)) >> 16;   // RNE
    return (unsigned short)r;
}
__device__ __forceinline__ float bf2f(unsigned short h) {
    union { unsigned u; float f; } c; c.u = ((unsigned)h) << 16;
    return c.f;
}

// ---------------- histogram ----------------

__global__ void k_zero(int* __restrict__ cnt, int n) {
    int i = blockIdx.x * blockDim.x + threadIdx.x;
    if (i < n) cnt[i] = 0;
}

__global__ void k_count(const int* __restrict__ ei, int* __restrict__ cnt, int E) {
    int e = blockIdx.x * blockDim.x + threadIdx.x;
    if (e < E) atomicAdd(&cnt[ei[E + e]], 1);  // dst = ei[1][e]
}

// ---------------- exclusive scan (3 kernels) ----------------

__global__ __launch_bounds__(256) void k_scan1(const int* __restrict__ cnt,
                                               int* __restrict__ pre,
                                               int* __restrict__ bsum, int n) {
    __shared__ int s[256];
    int t = threadIdx.x;
    int i = blockIdx.x * 256 + t;
    int v = (i < n) ? cnt[i] : 0;
    s[t] = v; __syncthreads();
    for (int off = 1; off < 256; off <<= 1) {
        int a = (t >= off) ? s[t - off] : 0;
        __syncthreads();
        s[t] += a;
        __syncthreads();
    }
    if (i < n) pre[i] = s[t] - v;
    if (t == 255) bsum[blockIdx.x] = s[255];
}

__global__ __launch_bounds__(512) void k_scan2(int* __restrict__ bsum,
                                               int* __restrict__ boff, int nb) {
    __shared__ int s[512];
    int t = threadIdx.x;
    int v = (t < nb) ? bsum[t] : 0;
    s[t] = v; __syncthreads();
    for (int off = 1; off < 512; off <<= 1) {
        int a = (t >= off) ? s[t - off] : 0;
        __syncthreads();
        s[t] += a;
        __syncthreads();
    }
    if (t < nb) boff[t] = s[t] - v;
}

__global__ __launch_bounds__(256) void k_scan3(const int* __restrict__ cnt,
                                               int* __restrict__ pre,
                                               const int* __restrict__ boff,
                                               int* __restrict__ cursor,
                                               float* __restrict__ dinv, int n) {
    int i = blockIdx.x * 256 + threadIdx.x;
    if (i < n) {
        int r = pre[i] + boff[blockIdx.x];
        pre[i] = r;
        cursor[i] = r;
        dinv[i] = rsqrtf((float)(cnt[i] + 1));
    }
}

// ---------------- CSR fill ----------------

__global__ void k_fill(const int* __restrict__ ei, int* __restrict__ cursor,
                       int* __restrict__ csr_src, int E) {
    int e = blockIdx.x * blockDim.x + threadIdx.x;
    if (e < E) {
        int src = ei[e];
        int dst = ei[E + e];
        int pos = atomicAdd(&cursor[dst], 1);
        csr_src[pos] = src;
    }
}

// ---------------- fused dense: g16 = bf16((xW)*dinv) ; out = xW_lin + b + b_lin + dinv*g ----------------

__global__ __launch_bounds__(256) void k_gemm(
    const float* __restrict__ x, const float* __restrict__ W,
    const float* __restrict__ b, const float* __restrict__ Wl,
    const float* __restrict__ bl, const float* __restrict__ dinv,
    unsigned short* __restrict__ g16, float* __restrict__ out, int n) {
    __shared__ float Ws[DIM * DIM];
    __shared__ float Wls[DIM * DIM];
    __shared__ float xs[4][DIM + 1];   // +1 pad: r-varying reads hit 4 banks, not 1

    for (int i = threadIdx.x; i < DIM * DIM; i += 256) {
        Ws[i]  = W[i];
        Wls[i] = Wl[i];
    }

    const int r = threadIdx.x >> 6;
    const int c = threadIdx.x & 63;
    const float bc = b[c] + bl[c];

    const int ntiles = (n + 3) >> 2;
    for (int tile = blockIdx.x; tile < ntiles; tile += gridDim.x) {
        const int row0 = tile * 4;
        __syncthreads();
        {
            int row = row0 + r;
            xs[r][c] = (row < n) ? x[row * DIM + c] : 0.0f;
        }
        __syncthreads();
        int row = row0 + r;
        if (row < n) {
            float acc = bc, accW = 0.0f;
#pragma unroll
            for (int k = 0; k < DIM; ++k) {
                float xv = xs[r][k];
                accW += xv * Ws[k * DIM + c];
                acc  += xv * Wls[k * DIM + c];
            }
            float dv = dinv[row];
            float gv = accW * dv;                 // dinv[src] folded into message
            g16[row * DIM + c] = f2bf(gv);
            out[row * DIM + c] = acc + dv * gv;   // self-loop term
        }
    }
}

// ---------------- gather: out[i] += dinv[i] * sum_j g[csr_src[j]] ----------------
// 1 wave/node; 4 x 16-lane groups each consume one edge-row per load (8 in flight).

__global__ __launch_bounds__(256) void k_gather(
    const int* __restrict__ rowptr, const int* __restrict__ cnt,
    const int* __restrict__ csr_src, const ushort4* __restrict__ g16,
    const float* __restrict__ dinv, float* __restrict__ out, int n) {
    int wid = blockIdx.x * 4 + (threadIdx.x >> 6);
    if (wid >= n) return;
    const int lane = threadIdx.x & 63;
    const int grp = lane >> 4;
    const int sub = lane & 15;
    const int start = rowptr[wid];
    const int m = cnt[wid];
    float ax = 0.f, ay = 0.f, az = 0.f, aw = 0.f;

    for (int base = 0; base < m; base += 64) {
        int rem = m - base; if (rem > 64) rem = 64;
        // one coalesced load covers up to 64 edge indices
        int srcv = (lane < rem) ? csr_src[start + base + lane] : 0;
        int nb4 = (rem + 3) >> 2;
        int bj = 0;
        for (; bj + 2 <= nb4; bj += 2) {
            int j0 = (bj << 2) + grp;
            int j1 = j0 + 4;
            int s0 = __shfl(srcv, j0);
            int s1 = __shfl(srcv, j1);
            ushort4 v0 = g16[s0 * 16 + sub];      // 16 lanes x 8B = full 128B row
            ushort4 v1 = g16[s1 * 16 + sub];
            if (j0 < rem) { ax += bf2f(v0.x); ay += bf2f(v0.y); az += bf2f(v0.z); aw += bf2f(v0.w); }
            if (j1 < rem) { ax += bf2f(v1.x); ay += bf2f(v1.y); az += bf2f(v1.z); aw += bf2f(v1.w); }
        }
        if (bj < nb4) {
            int j0 = (bj << 2) + grp;
            int s0 = __shfl(srcv, j0);
            ushort4 v0 = g16[s0 * 16 + sub];
            if (j0 < rem) { ax += bf2f(v0.x); ay += bf2f(v0.y); az += bf2f(v0.z); aw += bf2f(v0.w); }
        }
    }

    // reduce the 4 groups (lanes with equal sub)
    ax += __shfl_xor(ax, 16); ay += __shfl_xor(ay, 16);
    az += __shfl_xor(az, 16); aw += __shfl_xor(aw, 16);
    ax += __shfl_xor(ax, 32); ay += __shfl_xor(ay, 32);
    az += __shfl_xor(az, 32); aw += __shfl_xor(aw, 32);

    if (grp == 0) {
        float dv = dinv[wid];
        float4* op = (float4*)(out + (size_t)wid * DIM) + sub;
        float4 o = *op;
        o.x += dv * ax; o.y += dv * ay; o.z += dv * az; o.w += dv * aw;
        *op = o;
    }
}

// ---------------- launch ----------------

extern "C" void kernel_launch(void* const* d_in, const int* in_sizes, int n_in,
                              void* d_out, int out_size, void* d_ws, size_t ws_size,
                              hipStream_t stream) {
    const float* x  = (const float*)d_in[0];
    const int*   ei = (const int*)d_in[1];
    const float* W  = (const float*)d_in[2];
    const float* b  = (const float*)d_in[3];
    const float* Wl = (const float*)d_in[4];
    const float* bl = (const float*)d_in[5];
    float* out = (float*)d_out;

    char* ws = (char*)d_ws;
    int*   cnt     = (int*)(ws + 0);             // 400000 B
    int*   rowptr  = (int*)(ws + 400000);        // 400000 B
    int*   cursor  = (int*)(ws + 800000);        // 400000 B
    float* dinv    = (float*)(ws + 1200000);     // 400000 B
    int*   bsum    = (int*)(ws + 1600000);       // 4096 B
    int*   boff    = (int*)(ws + 1604096);       // 4096 B
    int*   csr_src = (int*)(ws + 1608192);       // 6400000 B
    unsigned short* g16 = (unsigned short*)(ws + 8008192);  // 12.8 MB, 8B-aligned

    k_zero <<<NB, 256, 0, stream>>>(cnt, NN);
    k_count<<<(NE + 255) / 256, 256, 0, stream>>>(ei, cnt, NE);
    k_scan1<<<NB, 256, 0, stream>>>(cnt, rowptr, bsum, NN);
    k_scan2<<<1, 512, 0, stream>>>(bsum, boff, NB);
    k_scan3<<<NB, 256, 0, stream>>>(cnt, rowptr, boff, cursor, dinv, NN);
    k_fill <<<(NE + 255) / 256, 256, 0, stream>>>(ei, cursor, csr_src, NE);
    k_gemm <<<2048, 256, 0, stream>>>(x, W, b, Wl, bl, dinv, g16, out, NN);
    k_gather<<<(NN + 3) / 4, 256, 0, stream>>>(rowptr, cnt, csr_src, (const ushort4*)g16, dinv, out, NN);
}

// Round 4
// 313.517 us; speedup vs baseline: 1.6262x; 1.0616x over previous
//
#include <hip/hip_runtime.h>

#define NN 100000
#define NE 1600000
#define DIM 64
#define NB 391          // ceil(NN/256)

__device__ __forceinline__ unsigned short f2bf(float f) {
    union { float f; unsigned u; } c; c.f = f;
    unsigned r = (c.u + 0x7FFFu + ((c.u >> 16) & 1u)) >> 16;   // RNE
    return (unsigned short)r;
}
__device__ __forceinline__ float bf2f(unsigned short h) {
    union { unsigned u; float f; } c; c.u = ((unsigned)h) << 16;
    return c.f;
}
__device__ __forceinline__ float lanebcast(float v, int k) {
    return __int_as_float(__builtin_amdgcn_readlane(__float_as_int(v), k));
}

// ---------------- histogram ----------------

__global__ void k_zero(int* __restrict__ cnt, int n) {
    int i = blockIdx.x * blockDim.x + threadIdx.x;
    if (i < n) cnt[i] = 0;
}

__global__ void k_count(const int* __restrict__ ei, int* __restrict__ cnt, int E) {
    int e = blockIdx.x * blockDim.x + threadIdx.x;
    if (e < E) atomicAdd(&cnt[ei[E + e]], 1);  // dst = ei[1][e]
}

// ---------------- exclusive scan (3 kernels) ----------------

__global__ __launch_bounds__(256) void k_scan1(const int* __restrict__ cnt,
                                               int* __restrict__ pre,
                                               int* __restrict__ bsum, int n) {
    __shared__ int s[256];
    int t = threadIdx.x;
    int i = blockIdx.x * 256 + t;
    int v = (i < n) ? cnt[i] : 0;
    s[t] = v; __syncthreads();
    for (int off = 1; off < 256; off <<= 1) {
        int a = (t >= off) ? s[t - off] : 0;
        __syncthreads();
        s[t] += a;
        __syncthreads();
    }
    if (i < n) pre[i] = s[t] - v;
    if (t == 255) bsum[blockIdx.x] = s[255];
}

__global__ __launch_bounds__(512) void k_scan2(int* __restrict__ bsum,
                                               int* __restrict__ boff, int nb) {
    __shared__ int s[512];
    int t = threadIdx.x;
    int v = (t < nb) ? bsum[t] : 0;
    s[t] = v; __syncthreads();
    for (int off = 1; off < 512; off <<= 1) {
        int a = (t >= off) ? s[t - off] : 0;
        __syncthreads();
        s[t] += a;
        __syncthreads();
    }
    if (t < nb) boff[t] = s[t] - v;
}

__global__ __launch_bounds__(256) void k_scan3(const int* __restrict__ cnt,
                                               int* __restrict__ pre,
                                               const int* __restrict__ boff,
                                               int* __restrict__ cursor,
                                               float* __restrict__ dinv, int n) {
    int i = blockIdx.x * 256 + threadIdx.x;
    if (i < n) {
        int r = pre[i] + boff[blockIdx.x];
        pre[i] = r;
        cursor[i] = r;
        dinv[i] = rsqrtf((float)(cnt[i] + 1));
    }
}

// ---------------- CSR fill (stores via atomicExch -> in-cache RMW, not
// partial-line HBM writes) ----------------

__global__ void k_fill(const int* __restrict__ ei, int* __restrict__ cursor,
                       int* __restrict__ csr_src, int E) {
    int e = blockIdx.x * blockDim.x + threadIdx.x;
    if (e < E) {
        int src = ei[e];
        int dst = ei[E + e];
        int pos = atomicAdd(&cursor[dst], 1);
        atomicExch(&csr_src[pos], src);
    }
}

// ---------------- fused dense: g16 = bf16((xW)*dinv) ; out = xW_lin + b + b_lin + dinv*g
// 4 rows/thread in registers, x broadcast via v_readlane (no LDS pipe), W in LDS.

__global__ __launch_bounds__(256) void k_gemm(
    const float* __restrict__ x, const float* __restrict__ W,
    const float* __restrict__ b, const float* __restrict__ Wl,
    const float* __restrict__ bl, const float* __restrict__ dinv,
    unsigned short* __restrict__ g16, float* __restrict__ out, int n) {
    __shared__ float Ws[DIM * DIM];
    __shared__ float Wls[DIM * DIM];

    for (int i = threadIdx.x; i < DIM * DIM; i += 256) {
        Ws[i]  = W[i];
        Wls[i] = Wl[i];
    }
    __syncthreads();

    const int w = threadIdx.x >> 6;
    const int c = threadIdx.x & 63;
    const float bc = b[c] + bl[c];

    const int ntiles = n >> 4;   // NN = 100000 = 16 * 6250, exact
    for (int tile = blockIdx.x; tile < ntiles; tile += gridDim.x) {
        const int row0 = (tile << 4) + (w << 2);   // this wave's 4 rows
        const float* xp = x + (size_t)row0 * DIM + c;
        float xv0 = xp[0 * DIM], xv1 = xp[1 * DIM], xv2 = xp[2 * DIM], xv3 = xp[3 * DIM];

        float a0 = 0.f, a1 = 0.f, a2 = 0.f, a3 = 0.f;
        float l0 = 0.f, l1 = 0.f, l2 = 0.f, l3 = 0.f;
#pragma unroll
        for (int k = 0; k < DIM; ++k) {
            float wV = Ws[k * DIM + c];
            float wL = Wls[k * DIM + c];
            float x0 = lanebcast(xv0, k);
            float x1 = lanebcast(xv1, k);
            float x2 = lanebcast(xv2, k);
            float x3 = lanebcast(xv3, k);
            a0 += x0 * wV; l0 += x0 * wL;
            a1 += x1 * wV; l1 += x1 * wL;
            a2 += x2 * wV; l2 += x2 * wL;
            a3 += x3 * wV; l3 += x3 * wL;
        }
        float aj[4] = {a0, a1, a2, a3};
        float lj[4] = {l0, l1, l2, l3};
#pragma unroll
        for (int j = 0; j < 4; ++j) {
            int row = row0 + j;
            float dv = dinv[row];
            float gv = aj[j] * dv;                 // dinv[src] folded into message
            g16[(size_t)row * DIM + c] = f2bf(gv);
            out[(size_t)row * DIM + c] = lj[j] + bc + dv * gv;  // self-loop + linear
        }
    }
}

// ---------------- gather: out[i] += dinv[i] * sum_j g[csr_src[j]] ----------------

__global__ __launch_bounds__(256) void k_gather(
    const int* __restrict__ rowptr, const int* __restrict__ cnt,
    const int* __restrict__ csr_src, const ushort4* __restrict__ g16,
    const float* __restrict__ dinv, float* __restrict__ out, int n) {
    int wid = blockIdx.x * 4 + (threadIdx.x >> 6);
    if (wid >= n) return;
    const int lane = threadIdx.x & 63;
    const int grp = lane >> 4;
    const int sub = lane & 15;
    const int start = rowptr[wid];
    const int m = cnt[wid];
    float ax = 0.f, ay = 0.f, az = 0.f, aw = 0.f;

    for (int base = 0; base < m; base += 64) {
        int rem = m - base; if (rem > 64) rem = 64;
        int srcv = (lane < rem) ? csr_src[start + base + lane] : 0;
        int nb4 = (rem + 3) >> 2;
        int bj = 0;
        for (; bj + 2 <= nb4; bj += 2) {
            int j0 = (bj << 2) + grp;
            int j1 = j0 + 4;
            int s0 = __shfl(srcv, j0);
            int s1 = __shfl(srcv, j1);
            ushort4 v0 = g16[s0 * 16 + sub];
            ushort4 v1 = g16[s1 * 16 + sub];
            if (j0 < rem) { ax += bf2f(v0.x); ay += bf2f(v0.y); az += bf2f(v0.z); aw += bf2f(v0.w); }
            if (j1 < rem) { ax += bf2f(v1.x); ay += bf2f(v1.y); az += bf2f(v1.z); aw += bf2f(v1.w); }
        }
        if (bj < nb4) {
            int j0 = (bj << 2) + grp;
            int s0 = __shfl(srcv, j0);
            ushort4 v0 = g16[s0 * 16 + sub];
            if (j0 < rem) { ax += bf2f(v0.x); ay += bf2f(v0.y); az += bf2f(v0.z); aw += bf2f(v0.w); }
        }
    }

    ax += __shfl_xor(ax, 16); ay += __shfl_xor(ay, 16);
    az += __shfl_xor(az, 16); aw += __shfl_xor(aw, 16);
    ax += __shfl_xor(ax, 32); ay += __shfl_xor(ay, 32);
    az += __shfl_xor(az, 32); aw += __shfl_xor(aw, 32);

    if (grp == 0) {
        float dv = dinv[wid];
        float4* op = (float4*)(out + (size_t)wid * DIM) + sub;
        float4 o = *op;
        o.x += dv * ax; o.y += dv * ay; o.z += dv * az; o.w += dv * aw;
        *op = o;
    }
}

// ---------------- launch ----------------

extern "C" void kernel_launch(void* const* d_in, const int* in_sizes, int n_in,
                              void* d_out, int out_size, void* d_ws, size_t ws_size,
                              hipStream_t stream) {
    const float* x  = (const float*)d_in[0];
    const int*   ei = (const int*)d_in[1];
    const float* W  = (const float*)d_in[2];
    const float* b  = (const float*)d_in[3];
    const float* Wl = (const float*)d_in[4];
    const float* bl = (const float*)d_in[5];
    float* out = (float*)d_out;

    char* ws = (char*)d_ws;
    int*   cnt     = (int*)(ws + 0);             // 400000 B
    int*   rowptr  = (int*)(ws + 400000);        // 400000 B
    int*   cursor  = (int*)(ws + 800000);        // 400000 B
    float* dinv    = (float*)(ws + 1200000);     // 400000 B
    int*   bsum    = (int*)(ws + 1600000);       // 4096 B
    int*   boff    = (int*)(ws + 1604096);       // 4096 B
    int*   csr_src = (int*)(ws + 1608192);       // 6400000 B
    unsigned short* g16 = (unsigned short*)(ws + 8008192);  // 12.8 MB, 8B-aligned

    k_zero <<<NB, 256, 0, stream>>>(cnt, NN);
    k_count<<<(NE + 255) / 256, 256, 0, stream>>>(ei, cnt, NE);
    k_scan1<<<NB, 256, 0, stream>>>(cnt, rowptr, bsum, NN);
    k_scan2<<<1, 512, 0, stream>>>(bsum, boff, NB);
    k_scan3<<<NB, 256, 0, stream>>>(cnt, rowptr, boff, cursor, dinv, NN);
    k_fill <<<(NE + 255) / 256, 256, 0, stream>>>(ei, cursor, csr_src, NE);
    k_gemm <<<2048, 256, 0, stream>>>(x, W, b, Wl, bl, dinv, g16, out, NN);
    k_gather<<<(NN + 3) / 4, 256, 0, stream>>>(rowptr, cnt, csr_src, (const ushort4*)g16, dinv, out, NN);
}

// Round 5
// 249.333 us; speedup vs baseline: 2.0448x; 1.2574x over previous
//
#include <hip/hip_runtime.h>

#define NN 100000
#define NE 1600000
#define DIM 64
#define NB 391          // ceil(NN/256)
#define FILL_BLOCKS 512 // 8 XCD groups x 64 blocks

__device__ __forceinline__ unsigned short f2bf(float f) {
    union { float f; unsigned u; } c; c.f = f;
    unsigned r = (c.u + 0x7FFFu + ((c.u >> 16) & 1u)) >> 16;   // RNE
    return (unsigned short)r;
}
__device__ __forceinline__ float bf2f(unsigned short h) {
    union { unsigned u; float f; } c; c.u = ((unsigned)h) << 16;
    return c.f;
}
__device__ __forceinline__ float lanebcast(float v, int k) {
    return __int_as_float(__builtin_amdgcn_readlane(__float_as_int(v), k));
}

// ---------------- histogram ----------------

__global__ void k_zero(int* __restrict__ cnt, int n) {
    int i = blockIdx.x * blockDim.x + threadIdx.x;
    if (i < n) cnt[i] = 0;
}

__global__ void k_count(const int* __restrict__ ei, int* __restrict__ cnt, int E) {
    int e = blockIdx.x * blockDim.x + threadIdx.x;
    if (e < E) atomicAdd(&cnt[ei[E + e]], 1);  // dst = ei[1][e]
}

// ---------------- exclusive scan (3 kernels) ----------------

__global__ __launch_bounds__(256) void k_scan1(const int* __restrict__ cnt,
                                               int* __restrict__ pre,
                                               int* __restrict__ bsum, int n) {
    __shared__ int s[256];
    int t = threadIdx.x;
    int i = blockIdx.x * 256 + t;
    int v = (i < n) ? cnt[i] : 0;
    s[t] = v; __syncthreads();
    for (int off = 1; off < 256; off <<= 1) {
        int a = (t >= off) ? s[t - off] : 0;
        __syncthreads();
        s[t] += a;
        __syncthreads();
    }
    if (i < n) pre[i] = s[t] - v;
    if (t == 255) bsum[blockIdx.x] = s[255];
}

__global__ __launch_bounds__(512) void k_scan2(int* __restrict__ bsum,
                                               int* __restrict__ boff, int nb) {
    __shared__ int s[512];
    int t = threadIdx.x;
    int v = (t < nb) ? bsum[t] : 0;
    s[t] = v; __syncthreads();
    for (int off = 1; off < 512; off <<= 1) {
        int a = (t >= off) ? s[t - off] : 0;
        __syncthreads();
        s[t] += a;
        __syncthreads();
    }
    if (t < nb) boff[t] = s[t] - v;
}

__global__ __launch_bounds__(256) void k_scan3(const int* __restrict__ cnt,
                                               int* __restrict__ pre,
                                               const int* __restrict__ boff,
                                               int* __restrict__ cursor,
                                               float* __restrict__ dinv, int n) {
    int i = blockIdx.x * 256 + threadIdx.x;
    if (i < n) {
        int r = pre[i] + boff[blockIdx.x];
        pre[i] = r;
        cursor[i] = r;
        dinv[i] = rsqrtf((float)(cnt[i] + 1));
    }
}

// ---------------- CSR fill, XCD-partitioned by dst range ----------------
// Block group x = blockIdx%8 (lands on XCD x under round-robin dispatch)
// handles only dst in [x*12500, (x+1)*12500): each XCD writes a private
// contiguous ~800KB csr slice -> full-line writebacks, no 8x amplification.

__global__ __launch_bounds__(256) void k_fill(const int* __restrict__ ei,
                                              int* __restrict__ cursor,
                                              int* __restrict__ csr_src, int E) {
    const int x   = blockIdx.x & 7;        // XCD group
    const int gj  = blockIdx.x >> 3;       // block index within group
    const int step = (FILL_BLOCKS >> 3) * 256;
    const int lo = x * (NN / 8);
    const int hi = lo + (NN / 8);
    for (int e = gj * 256 + threadIdx.x; e < E; e += step) {
        int dst = ei[E + e];
        if (dst >= lo && dst < hi) {
            int src = ei[e];
            int pos = atomicAdd(&cursor[dst], 1);
            csr_src[pos] = src;
        }
    }
}

// ---------------- fused dense: g16 = bf16((xW)*dinv) ; out = xW_lin + b + b_lin + dinv*g

__global__ __launch_bounds__(256) void k_gemm(
    const float* __restrict__ x, const float* __restrict__ W,
    const float* __restrict__ b, const float* __restrict__ Wl,
    const float* __restrict__ bl, const float* __restrict__ dinv,
    unsigned short* __restrict__ g16, float* __restrict__ out, int n) {
    __shared__ float Ws[DIM * DIM];
    __shared__ float Wls[DIM * DIM];

    for (int i = threadIdx.x; i < DIM * DIM; i += 256) {
        Ws[i]  = W[i];
        Wls[i] = Wl[i];
    }
    __syncthreads();

    const int w = threadIdx.x >> 6;
    const int c = threadIdx.x & 63;
    const float bc = b[c] + bl[c];

    const int ntiles = n >> 4;   // NN = 16 * 6250, exact
    for (int tile = blockIdx.x; tile < ntiles; tile += gridDim.x) {
        const int row0 = (tile << 4) + (w << 2);
        const float* xp = x + (size_t)row0 * DIM + c;
        float xv0 = xp[0 * DIM], xv1 = xp[1 * DIM], xv2 = xp[2 * DIM], xv3 = xp[3 * DIM];

        float a0 = 0.f, a1 = 0.f, a2 = 0.f, a3 = 0.f;
        float l0 = 0.f, l1 = 0.f, l2 = 0.f, l3 = 0.f;
#pragma unroll
        for (int k = 0; k < DIM; ++k) {
            float wV = Ws[k * DIM + c];
            float wL = Wls[k * DIM + c];
            float x0 = lanebcast(xv0, k);
            float x1 = lanebcast(xv1, k);
            float x2 = lanebcast(xv2, k);
            float x3 = lanebcast(xv3, k);
            a0 += x0 * wV; l0 += x0 * wL;
            a1 += x1 * wV; l1 += x1 * wL;
            a2 += x2 * wV; l2 += x2 * wL;
            a3 += x3 * wV; l3 += x3 * wL;
        }
        float aj[4] = {a0, a1, a2, a3};
        float lj[4] = {l0, l1, l2, l3};
#pragma unroll
        for (int j = 0; j < 4; ++j) {
            int row = row0 + j;
            float dv = dinv[row];
            float gv = aj[j] * dv;
            g16[(size_t)row * DIM + c] = f2bf(gv);
            out[(size_t)row * DIM + c] = lj[j] + bc + dv * gv;
        }
    }
}

// ---------------- gather: out[i] += dinv[i] * sum_j g[csr_src[j]] ----------------

__global__ __launch_bounds__(256) void k_gather(
    const int* __restrict__ rowptr, const int* __restrict__ cnt,
    const int* __restrict__ csr_src, const ushort4* __restrict__ g16,
    const float* __restrict__ dinv, float* __restrict__ out, int n) {
    int wid = blockIdx.x * 4 + (threadIdx.x >> 6);
    if (wid >= n) return;
    const int lane = threadIdx.x & 63;
    const int grp = lane >> 4;
    const int sub = lane & 15;
    const int start = rowptr[wid];
    const int m = cnt[wid];
    float ax = 0.f, ay = 0.f, az = 0.f, aw = 0.f;

    for (int base = 0; base < m; base += 64) {
        int rem = m - base; if (rem > 64) rem = 64;
        int srcv = (lane < rem) ? csr_src[start + base + lane] : 0;
        int nb4 = (rem + 3) >> 2;
        int bj = 0;
        for (; bj + 2 <= nb4; bj += 2) {
            int j0 = (bj << 2) + grp;
            int j1 = j0 + 4;
            int s0 = __shfl(srcv, j0);
            int s1 = __shfl(srcv, j1);
            ushort4 v0 = g16[s0 * 16 + sub];
            ushort4 v1 = g16[s1 * 16 + sub];
            if (j0 < rem) { ax += bf2f(v0.x); ay += bf2f(v0.y); az += bf2f(v0.z); aw += bf2f(v0.w); }
            if (j1 < rem) { ax += bf2f(v1.x); ay += bf2f(v1.y); az += bf2f(v1.z); aw += bf2f(v1.w); }
        }
        if (bj < nb4) {
            int j0 = (bj << 2) + grp;
            int s0 = __shfl(srcv, j0);
            ushort4 v0 = g16[s0 * 16 + sub];
            if (j0 < rem) { ax += bf2f(v0.x); ay += bf2f(v0.y); az += bf2f(v0.z); aw += bf2f(v0.w); }
        }
    }

    ax += __shfl_xor(ax, 16); ay += __shfl_xor(ay, 16);
    az += __shfl_xor(az, 16); aw += __shfl_xor(aw, 16);
    ax += __shfl_xor(ax, 32); ay += __shfl_xor(ay, 32);
    az += __shfl_xor(az, 32); aw += __shfl_xor(aw, 32);

    if (grp == 0) {
        float dv = dinv[wid];
        float4* op = (float4*)(out + (size_t)wid * DIM) + sub;
        float4 o = *op;
        o.x += dv * ax; o.y += dv * ay; o.z += dv * az; o.w += dv * aw;
        *op = o;
    }
}

// ---------------- launch ----------------

extern "C" void kernel_launch(void* const* d_in, const int* in_sizes, int n_in,
                              void* d_out, int out_size, void* d_ws, size_t ws_size,
                              hipStream_t stream) {
    const float* x  = (const float*)d_in[0];
    const int*   ei = (const int*)d_in[1];
    const float* W  = (const float*)d_in[2];
    const float* b  = (const float*)d_in[3];
    const float* Wl = (const float*)d_in[4];
    const float* bl = (const float*)d_in[5];
    float* out = (float*)d_out;

    char* ws = (char*)d_ws;
    int*   cnt     = (int*)(ws + 0);             // 400000 B
    int*   rowptr  = (int*)(ws + 400000);        // 400000 B
    int*   cursor  = (int*)(ws + 800000);        // 400000 B
    float* dinv    = (float*)(ws + 1200000);     // 400000 B
    int*   bsum    = (int*)(ws + 1600000);       // 4096 B
    int*   boff    = (int*)(ws + 1604096);       // 4096 B
    int*   csr_src = (int*)(ws + 1608192);       // 6400000 B
    unsigned short* g16 = (unsigned short*)(ws + 8008192);  // 12.8 MB, 8B-aligned

    k_zero <<<NB, 256, 0, stream>>>(cnt, NN);
    k_count<<<(NE + 255) / 256, 256, 0, stream>>>(ei, cnt, NE);
    k_scan1<<<NB, 256, 0, stream>>>(cnt, rowptr, bsum, NN);
    k_scan2<<<1, 512, 0, stream>>>(bsum, boff, NB);
    k_scan3<<<NB, 256, 0, stream>>>(cnt, rowptr, boff, cursor, dinv, NN);
    k_fill <<<FILL_BLOCKS, 256, 0, stream>>>(ei, cursor, csr_src, NE);
    k_gemm <<<2048, 256, 0, stream>>>(x, W, b, Wl, bl, dinv, g16, out, NN);
    k_gather<<<(NN + 3) / 4, 256, 0, stream>>>(rowptr, cnt, csr_src, (const ushort4*)g16, dinv, out, NN);
}

// Round 6
// 202.602 us; speedup vs baseline: 2.5165x; 1.2307x over previous
//
#include <hip/hip_runtime.h>

#define NN 100000
#define NE 1600000
#define DIM 64
#define K 782            // buckets of 128 nodes: b = dst >> 7
#define ABLK 8192        // edges per binning tile
#define NTILE 196        // ceil(NE / ABLK)
#define GCAP 2600        // per-bucket edge capacity (mean 2046, sigma 45)

__device__ __forceinline__ unsigned short f2bf(float f) {
    union { float f; unsigned u; } c; c.f = f;
    unsigned r = (c.u + 0x7FFFu + ((c.u >> 16) & 1u)) >> 16;   // RNE
    return (unsigned short)r;
}
__device__ __forceinline__ float bf2f(unsigned short h) {
    union { unsigned u; float f; } c; c.u = ((unsigned)h) << 16;
    return c.f;
}
__device__ __forceinline__ float lanebcast(float v, int k) {
    return __int_as_float(__builtin_amdgcn_readlane(__float_as_int(v), k));
}

// ---------------- degree histogram ----------------

__global__ void k_zero(int* __restrict__ cnt, int n) {
    int i = blockIdx.x * blockDim.x + threadIdx.x;
    if (i < n) cnt[i] = 0;
}

__global__ void k_count(const int* __restrict__ ei, int* __restrict__ cnt, int E) {
    int e = blockIdx.x * blockDim.x + threadIdx.x;
    if (e < E) atomicAdd(&cnt[ei[E + e]], 1);  // dst = ei[1][e]
}

// ---------------- dinv + per-bucket edge totals ----------------

__global__ __launch_bounds__(256) void k_prep(const int* __restrict__ cnt,
                                              float* __restrict__ dinv,
                                              int* __restrict__ bucket_cnt) {
    __shared__ int red[256];
    int tid = threadIdx.x;
    int i = blockIdx.x * 256 + tid;
    int c = (i < NN) ? cnt[i] : 0;
    if (i < NN) dinv[i] = rsqrtf((float)(c + 1));
    red[tid] = c;
    __syncthreads();
    for (int off = 64; off >= 1; off >>= 1) {
        if ((tid & 127) < off) red[tid] += red[tid + off];
        __syncthreads();
    }
    if ((tid & 127) == 0) bucket_cnt[blockIdx.x * 2 + (tid >> 7)] = red[tid];
}

// ---------------- scan bucket totals -> boff, init gcur ----------------

__global__ __launch_bounds__(1024) void k_bscan(const int* __restrict__ bucket_cnt,
                                                int* __restrict__ boff,
                                                int* __restrict__ gcur) {
    __shared__ int s[1024];
    int t = threadIdx.x;
    int v = (t < K) ? bucket_cnt[t] : 0;
    s[t] = v;
    __syncthreads();
    for (int off = 1; off < 1024; off <<= 1) {
        int a = (t >= off) ? s[t - off] : 0;
        __syncthreads();
        s[t] += a;
        __syncthreads();
    }
    if (t < K) {
        int ex = s[t] - v;
        boff[t] = ex;
        gcur[t] = ex;
        if (t == K - 1) boff[K] = s[t];   // == NE
    }
}

// ---------------- Phase A: bin edges by bucket, coalesced run writes ----------------

__global__ __launch_bounds__(1024) void k_binA(const int* __restrict__ ei,
                                               int* __restrict__ gcur,
                                               unsigned* __restrict__ ebuf, int E) {
    __shared__ int hist[1024];               // counts, then inclusive scan
    __shared__ int hoff[K];                  // run start within tile
    __shared__ int gbase[K];                 // claimed global base
    __shared__ int lcur[K];
    __shared__ unsigned sbufE[ABLK];         // packed (ldst<<17)|src, bucket-sorted
    __shared__ unsigned short sbufB[ABLK];   // bucket id per entry

    const int tid = threadIdx.x;
    const int e0 = blockIdx.x * ABLK;
    const int nval = min(ABLK, E - e0);

    hist[tid] = 0;
    __syncthreads();

    // pass 1: count (keep edges in registers)
    int src_[8]; int pk_[8]; int b_[8]; int myN = 0;
#pragma unroll
    for (int i = 0; i < 8; ++i) {
        int e = e0 + i * 1024 + tid;
        if (e < E) {
            int dst = ei[E + e];
            int src = ei[e];
            int b = dst >> 7;
            src_[myN] = src;
            pk_[myN]  = ((dst & 127) << 17) | src;
            b_[myN]   = b;
            ++myN;
            atomicAdd(&hist[b], 1);
        }
    }
    __syncthreads();

    int cntv = hist[tid];
    __syncthreads();
    for (int off = 1; off < 1024; off <<= 1) {
        int a = (tid >= off) ? hist[tid - off] : 0;
        __syncthreads();
        hist[tid] += a;
        __syncthreads();
    }
    if (tid < K) {
        int ho = hist[tid] - cntv;
        hoff[tid] = ho;
        lcur[tid] = ho;
        gbase[tid] = (cntv > 0) ? atomicAdd(&gcur[tid], cntv) : 0;
    }
    __syncthreads();

    // pass 2: place into LDS, bucket-sorted
    for (int j = 0; j < myN; ++j) {
        int pos = atomicAdd(&lcur[b_[j]], 1);
        sbufE[pos] = (unsigned)pk_[j];
        sbufB[pos] = (unsigned short)b_[j];
    }
    __syncthreads();

    // pass 3: coalesced run writes
    for (int j = tid; j < nval; j += 1024) {
        unsigned en = sbufE[j];
        int b = sbufB[j];
        ebuf[gbase[b] + (j - hoff[b])] = en;
    }
}

// ---------------- fused dense: g16 = bf16((xW)*dinv) ; out = xW_lin + b + b_lin + dinv*g

__global__ __launch_bounds__(256) void k_gemm(
    const float* __restrict__ x, const float* __restrict__ W,
    const float* __restrict__ b, const float* __restrict__ Wl,
    const float* __restrict__ bl, const float* __restrict__ dinv,
    unsigned short* __restrict__ g16, float* __restrict__ out, int n) {
    __shared__ float Ws[DIM * DIM];
    __shared__ float Wls[DIM * DIM];

    for (int i = threadIdx.x; i < DIM * DIM; i += 256) {
        Ws[i]  = W[i];
        Wls[i] = Wl[i];
    }
    __syncthreads();

    const int w = threadIdx.x >> 6;
    const int c = threadIdx.x & 63;
    const float bc = b[c] + bl[c];

    const int ntiles = n >> 4;   // NN = 16 * 6250, exact
    for (int tile = blockIdx.x; tile < ntiles; tile += gridDim.x) {
        const int row0 = (tile << 4) + (w << 2);
        const float* xp = x + (size_t)row0 * DIM + c;
        float xv0 = xp[0 * DIM], xv1 = xp[1 * DIM], xv2 = xp[2 * DIM], xv3 = xp[3 * DIM];

        float a0 = 0.f, a1 = 0.f, a2 = 0.f, a3 = 0.f;
        float l0 = 0.f, l1 = 0.f, l2 = 0.f, l3 = 0.f;
#pragma unroll
        for (int k = 0; k < DIM; ++k) {
            float wV = Ws[k * DIM + c];
            float wL = Wls[k * DIM + c];
            float x0 = lanebcast(xv0, k);
            float x1 = lanebcast(xv1, k);
            float x2 = lanebcast(xv2, k);
            float x3 = lanebcast(xv3, k);
            a0 += x0 * wV; l0 += x0 * wL;
            a1 += x1 * wV; l1 += x1 * wL;
            a2 += x2 * wV; l2 += x2 * wL;
            a3 += x3 * wV; l3 += x3 * wL;
        }
        float aj[4] = {a0, a1, a2, a3};
        float lj[4] = {l0, l1, l2, l3};
#pragma unroll
        for (int j = 0; j < 4; ++j) {
            int row = row0 + j;
            float dv = dinv[row];
            float gv = aj[j] * dv;
            g16[(size_t)row * DIM + c] = f2bf(gv);
            out[(size_t)row * DIM + c] = lj[j] + bc + dv * gv;
        }
    }
}

// ---------------- Phase B: LDS-local CSR + gather ----------------

__global__ __launch_bounds__(256) void k_gatherB(
    const int* __restrict__ cnt, const int* __restrict__ boff,
    const unsigned* __restrict__ ebuf, const ushort4* __restrict__ g16,
    const float* __restrict__ dinv, float* __restrict__ out) {
    __shared__ int sS[128];
    __shared__ int lptr[128];
    __shared__ int lcur[128];
    __shared__ unsigned lsrc[GCAP];

    const int tid = threadIdx.x;
    const int lo = blockIdx.x << 7;

    int c = 0;
    if (tid < 128) {
        int nd = lo + tid;
        c = (nd < NN) ? cnt[nd] : 0;
        sS[tid] = c;
    }
    __syncthreads();
    for (int off = 1; off < 128; off <<= 1) {
        int a = (tid < 128 && tid >= off) ? sS[tid - off] : 0;
        __syncthreads();
        if (tid < 128) sS[tid] += a;
        __syncthreads();
    }
    if (tid < 128) {
        int ex = sS[tid] - c;
        lptr[tid] = ex;
        lcur[tid] = ex;
    }
    __syncthreads();

    const int base = boff[blockIdx.x];
    const int mB = boff[blockIdx.x + 1] - base;

    for (int i = tid; i < mB; i += 256) {
        unsigned en = ebuf[base + i];
        int ld = en >> 17;
        int pos = atomicAdd(&lcur[ld], 1);
        lsrc[pos] = en & 0x1FFFFu;
    }
    __syncthreads();

    const int w = tid >> 6;
    const int lane = tid & 63;
    const int grp = lane >> 4;
    const int sub = lane & 15;

    for (int node = w; node < 128; node += 4) {
        int gnode = lo + node;
        if (gnode >= NN) continue;
        int start = lptr[node];
        int m = lcur[node] - start;

        float ax = 0.f, ay = 0.f, az = 0.f, aw = 0.f;
        for (int b2 = 0; b2 < m; b2 += 64) {
            int rem = m - b2; if (rem > 64) rem = 64;
            int srcv = (lane < rem) ? (int)lsrc[start + b2 + lane] : 0;
            int nb4 = (rem + 3) >> 2;
            int bj = 0;
            for (; bj + 2 <= nb4; bj += 2) {
                int j0 = (bj << 2) + grp;
                int j1 = j0 + 4;
                int s0 = __shfl(srcv, j0);
                int s1 = __shfl(srcv, j1);
                ushort4 v0 = g16[s0 * 16 + sub];
                ushort4 v1 = g16[s1 * 16 + sub];
                if (j0 < rem) { ax += bf2f(v0.x); ay += bf2f(v0.y); az += bf2f(v0.z); aw += bf2f(v0.w); }
                if (j1 < rem) { ax += bf2f(v1.x); ay += bf2f(v1.y); az += bf2f(v1.z); aw += bf2f(v1.w); }
            }
            if (bj < nb4) {
                int j0 = (bj << 2) + grp;
                int s0 = __shfl(srcv, j0);
                ushort4 v0 = g16[s0 * 16 + sub];
                if (j0 < rem) { ax += bf2f(v0.x); ay += bf2f(v0.y); az += bf2f(v0.z); aw += bf2f(v0.w); }
            }
        }

        ax += __shfl_xor(ax, 16); ay += __shfl_xor(ay, 16);
        az += __shfl_xor(az, 16); aw += __shfl_xor(aw, 16);
        ax += __shfl_xor(ax, 32); ay += __shfl_xor(ay, 32);
        az += __shfl_xor(az, 32); aw += __shfl_xor(aw, 32);

        if (grp == 0) {
            float dv = dinv[gnode];
            float4* op = (float4*)(out + (size_t)gnode * DIM) + sub;
            float4 o = *op;
            o.x += dv * ax; o.y += dv * ay; o.z += dv * az; o.w += dv * aw;
            *op = o;
        }
    }
}

// ---------------- launch ----------------

extern "C" void kernel_launch(void* const* d_in, const int* in_sizes, int n_in,
                              void* d_out, int out_size, void* d_ws, size_t ws_size,
                              hipStream_t stream) {
    const float* x  = (const float*)d_in[0];
    const int*   ei = (const int*)d_in[1];
    const float* W  = (const float*)d_in[2];
    const float* b  = (const float*)d_in[3];
    const float* Wl = (const float*)d_in[4];
    const float* bl = (const float*)d_in[5];
    float* out = (float*)d_out;

    char* ws = (char*)d_ws;
    int*      cnt        = (int*)(ws + 0);         // 400000 B
    float*    dinv       = (float*)(ws + 400000);  // 400000 B
    int*      bucket_cnt = (int*)(ws + 800000);    // 3128 B
    int*      boff       = (int*)(ws + 803200);    // 3132 B
    int*      gcur       = (int*)(ws + 806400);    // 3128 B
    unsigned* ebuf       = (unsigned*)(ws + 1048576);   // 6.4 MB
    unsigned short* g16  = (unsigned short*)(ws + 7448576);  // 12.8 MB, 8B-aligned

    k_zero <<<(NN + 255) / 256, 256, 0, stream>>>(cnt, NN);
    k_count<<<(NE + 255) / 256, 256, 0, stream>>>(ei, cnt, NE);
    k_prep <<<391, 256, 0, stream>>>(cnt, dinv, bucket_cnt);
    k_bscan<<<1, 1024, 0, stream>>>(bucket_cnt, boff, gcur);
    k_binA <<<NTILE, 1024, 0, stream>>>(ei, gcur, ebuf, NE);
    k_gemm <<<2048, 256, 0, stream>>>(x, W, b, Wl, bl, dinv, g16, out, NN);
    k_gatherB<<<K, 256, 0, stream>>>(cnt, boff, ebuf, (const ushort4*)g16, dinv, out);
}

// Round 7
// 177.823 us; speedup vs baseline: 2.8672x; 1.1393x over previous
//
#include <hip/hip_runtime.h>

#define NN 100000
#define NE 1600000
#define DIM 64
#define K 782            // buckets of 128 nodes: b = dst >> 7
#define ABLK 8192        // edges per binning tile
#define NTILE 196        // ceil(NE / ABLK)
#define GCAP 2600        // per-bucket edge capacity (mean 2046, sigma 45)

__device__ __forceinline__ unsigned short f2bf(float f) {
    union { float f; unsigned u; } c; c.f = f;
    unsigned r = (c.u + 0x7FFFu + ((c.u >> 16) & 1u)) >> 16;   // RNE
    return (unsigned short)r;
}
__device__ __forceinline__ float bf2f(unsigned short h) {
    union { unsigned u; float f; } c; c.u = ((unsigned)h) << 16;
    return c.f;
}
__device__ __forceinline__ float lanebcast(float v, int k) {
    return __int_as_float(__builtin_amdgcn_readlane(__float_as_int(v), k));
}

// ---------------- degree histogram ----------------

__global__ void k_zero(int* __restrict__ cnt, int n) {
    int i = blockIdx.x * blockDim.x + threadIdx.x;
    if (i < n) cnt[i] = 0;
}

__global__ void k_count(const int* __restrict__ ei, int* __restrict__ cnt, int E) {
    int e = blockIdx.x * blockDim.x + threadIdx.x;
    if (e < E) atomicAdd(&cnt[ei[E + e]], 1);  // dst = ei[1][e]
}

// ---------------- dinv + per-bucket edge totals ----------------

__global__ __launch_bounds__(256) void k_prep(const int* __restrict__ cnt,
                                              float* __restrict__ dinv,
                                              int* __restrict__ bucket_cnt) {
    __shared__ int red[256];
    int tid = threadIdx.x;
    int i = blockIdx.x * 256 + tid;
    int c = (i < NN) ? cnt[i] : 0;
    if (i < NN) dinv[i] = rsqrtf((float)(c + 1));
    red[tid] = c;
    __syncthreads();
    for (int off = 64; off >= 1; off >>= 1) {
        if ((tid & 127) < off) red[tid] += red[tid + off];
        __syncthreads();
    }
    if ((tid & 127) == 0) bucket_cnt[blockIdx.x * 2 + (tid >> 7)] = red[tid];
}

// ---------------- scan bucket totals -> boff, init gcur ----------------

__global__ __launch_bounds__(1024) void k_bscan(const int* __restrict__ bucket_cnt,
                                                int* __restrict__ boff,
                                                int* __restrict__ gcur) {
    __shared__ int s[1024];
    int t = threadIdx.x;
    int v = (t < K) ? bucket_cnt[t] : 0;
    s[t] = v;
    __syncthreads();
    for (int off = 1; off < 1024; off <<= 1) {
        int a = (t >= off) ? s[t - off] : 0;
        __syncthreads();
        s[t] += a;
        __syncthreads();
    }
    if (t < K) {
        int ex = s[t] - v;
        boff[t] = ex;
        gcur[t] = ex;
        if (t == K - 1) boff[K] = s[t];   // == NE
    }
}

// ---------------- Phase A: bin edges by bucket, coalesced run writes ----------------

__global__ __launch_bounds__(1024) void k_binA(const int* __restrict__ ei,
                                               int* __restrict__ gcur,
                                               unsigned* __restrict__ ebuf, int E) {
    __shared__ int hist[1024];               // counts, then inclusive scan
    __shared__ int hoff[K];                  // run start within tile
    __shared__ int gbase[K];                 // claimed global base
    __shared__ int lcur[K];
    __shared__ unsigned sbufE[ABLK];         // packed (ldst<<17)|src, bucket-sorted
    __shared__ unsigned short sbufB[ABLK];   // bucket id per entry

    const int tid = threadIdx.x;
    const int e0 = blockIdx.x * ABLK;
    const int nval = min(ABLK, E - e0);

    hist[tid] = 0;
    __syncthreads();

    // pass 1: count (keep edges in registers)
    int src_[8]; int pk_[8]; int b_[8]; int myN = 0;
#pragma unroll
    for (int i = 0; i < 8; ++i) {
        int e = e0 + i * 1024 + tid;
        if (e < E) {
            int dst = ei[E + e];
            int src = ei[e];
            int b = dst >> 7;
            src_[myN] = src;
            pk_[myN]  = ((dst & 127) << 17) | src;
            b_[myN]   = b;
            ++myN;
            atomicAdd(&hist[b], 1);
        }
    }
    __syncthreads();

    int cntv = hist[tid];
    __syncthreads();
    for (int off = 1; off < 1024; off <<= 1) {
        int a = (tid >= off) ? hist[tid - off] : 0;
        __syncthreads();
        hist[tid] += a;
        __syncthreads();
    }
    if (tid < K) {
        int ho = hist[tid] - cntv;
        hoff[tid] = ho;
        lcur[tid] = ho;
        gbase[tid] = (cntv > 0) ? atomicAdd(&gcur[tid], cntv) : 0;
    }
    __syncthreads();

    // pass 2: place into LDS, bucket-sorted
    for (int j = 0; j < myN; ++j) {
        int pos = atomicAdd(&lcur[b_[j]], 1);
        sbufE[pos] = (unsigned)pk_[j];
        sbufB[pos] = (unsigned short)b_[j];
    }
    __syncthreads();

    // pass 3: coalesced run writes
    for (int j = tid; j < nval; j += 1024) {
        unsigned en = sbufE[j];
        int b = sbufB[j];
        ebuf[gbase[b] + (j - hoff[b])] = en;
    }
}

// ---------------- fused dense: g16 = bf16((xW)*dinv) ; out = xW_lin + b + b_lin + dinv*g

__global__ __launch_bounds__(256) void k_gemm(
    const float* __restrict__ x, const float* __restrict__ W,
    const float* __restrict__ b, const float* __restrict__ Wl,
    const float* __restrict__ bl, const float* __restrict__ dinv,
    unsigned short* __restrict__ g16, float* __restrict__ out, int n) {
    __shared__ float Ws[DIM * DIM];
    __shared__ float Wls[DIM * DIM];

    for (int i = threadIdx.x; i < DIM * DIM; i += 256) {
        Ws[i]  = W[i];
        Wls[i] = Wl[i];
    }
    __syncthreads();

    const int w = threadIdx.x >> 6;
    const int c = threadIdx.x & 63;
    const float bc = b[c] + bl[c];

    const int ntiles = n >> 4;   // NN = 16 * 6250, exact
    for (int tile = blockIdx.x; tile < ntiles; tile += gridDim.x) {
        const int row0 = (tile << 4) + (w << 2);
        const float* xp = x + (size_t)row0 * DIM + c;
        float xv0 = xp[0 * DIM], xv1 = xp[1 * DIM], xv2 = xp[2 * DIM], xv3 = xp[3 * DIM];

        float a0 = 0.f, a1 = 0.f, a2 = 0.f, a3 = 0.f;
        float l0 = 0.f, l1 = 0.f, l2 = 0.f, l3 = 0.f;
#pragma unroll
        for (int k = 0; k < DIM; ++k) {
            float wV = Ws[k * DIM + c];
            float wL = Wls[k * DIM + c];
            float x0 = lanebcast(xv0, k);
            float x1 = lanebcast(xv1, k);
            float x2 = lanebcast(xv2, k);
            float x3 = lanebcast(xv3, k);
            a0 += x0 * wV; l0 += x0 * wL;
            a1 += x1 * wV; l1 += x1 * wL;
            a2 += x2 * wV; l2 += x2 * wL;
            a3 += x3 * wV; l3 += x3 * wL;
        }
        float aj[4] = {a0, a1, a2, a3};
        float lj[4] = {l0, l1, l2, l3};
#pragma unroll
        for (int j = 0; j < 4; ++j) {
            int row = row0 + j;
            float dv = dinv[row];
            float gv = aj[j] * dv;
            g16[(size_t)row * DIM + c] = f2bf(gv);
            out[(size_t)row * DIM + c] = lj[j] + bc + dv * gv;
        }
    }
}

// ---------------- Phase B: LDS-local CSR + gather (512 thr = 8 waves/block) ----------------

__global__ __launch_bounds__(512) void k_gatherB(
    const int* __restrict__ cnt, const int* __restrict__ boff,
    const unsigned* __restrict__ ebuf, const ushort4* __restrict__ g16,
    const float* __restrict__ dinv, float* __restrict__ out) {
    __shared__ int sS[128];
    __shared__ int lptr[128];
    __shared__ int lcur[128];
    __shared__ unsigned lsrc[GCAP];

    const int tid = threadIdx.x;
    const int lo = blockIdx.x << 7;

    int c = 0;
    if (tid < 128) {
        int nd = lo + tid;
        c = (nd < NN) ? cnt[nd] : 0;
        sS[tid] = c;
    }
    __syncthreads();
    for (int off = 1; off < 128; off <<= 1) {
        int a = (tid < 128 && tid >= off) ? sS[tid - off] : 0;
        __syncthreads();
        if (tid < 128) sS[tid] += a;
        __syncthreads();
    }
    if (tid < 128) {
        int ex = sS[tid] - c;
        lptr[tid] = ex;
        lcur[tid] = ex;
    }
    __syncthreads();

    const int base = boff[blockIdx.x];
    const int mB = boff[blockIdx.x + 1] - base;

    for (int i = tid; i < mB; i += 512) {
        unsigned en = ebuf[base + i];
        int ld = en >> 17;
        int pos = atomicAdd(&lcur[ld], 1);
        lsrc[pos] = en & 0x1FFFFu;
    }
    __syncthreads();

    const int w = tid >> 6;
    const int lane = tid & 63;
    const int grp = lane >> 4;
    const int sub = lane & 15;

    for (int node = w; node < 128; node += 8) {
        int gnode = lo + node;
        if (gnode >= NN) continue;
        int start = lptr[node];
        int m = lcur[node] - start;

        float ax = 0.f, ay = 0.f, az = 0.f, aw = 0.f;
        for (int b2 = 0; b2 < m; b2 += 64) {
            int rem = m - b2; if (rem > 64) rem = 64;
            int srcv = (lane < rem) ? (int)lsrc[start + b2 + lane] : 0;
            int nb4 = (rem + 3) >> 2;
            int bj = 0;
            for (; bj + 2 <= nb4; bj += 2) {
                int j0 = (bj << 2) + grp;
                int j1 = j0 + 4;
                int s0 = __shfl(srcv, j0);
                int s1 = __shfl(srcv, j1);
                ushort4 v0 = g16[s0 * 16 + sub];
                ushort4 v1 = g16[s1 * 16 + sub];
                if (j0 < rem) { ax += bf2f(v0.x); ay += bf2f(v0.y); az += bf2f(v0.z); aw += bf2f(v0.w); }
                if (j1 < rem) { ax += bf2f(v1.x); ay += bf2f(v1.y); az += bf2f(v1.z); aw += bf2f(v1.w); }
            }
            if (bj < nb4) {
                int j0 = (bj << 2) + grp;
                int s0 = __shfl(srcv, j0);
                ushort4 v0 = g16[s0 * 16 + sub];
                if (j0 < rem) { ax += bf2f(v0.x); ay += bf2f(v0.y); az += bf2f(v0.z); aw += bf2f(v0.w); }
            }
        }

        ax += __shfl_xor(ax, 16); ay += __shfl_xor(ay, 16);
        az += __shfl_xor(az, 16); aw += __shfl_xor(aw, 16);
        ax += __shfl_xor(ax, 32); ay += __shfl_xor(ay, 32);
        az += __shfl_xor(az, 32); aw += __shfl_xor(aw, 32);

        if (grp == 0) {
            float dv = dinv[gnode];
            float4* op = (float4*)(out + (size_t)gnode * DIM) + sub;
            float4 o = *op;
            o.x += dv * ax; o.y += dv * ay; o.z += dv * az; o.w += dv * aw;
            *op = o;
        }
    }
}

// ---------------- launch ----------------

extern "C" void kernel_launch(void* const* d_in, const int* in_sizes, int n_in,
                              void* d_out, int out_size, void* d_ws, size_t ws_size,
                              hipStream_t stream) {
    const float* x  = (const float*)d_in[0];
    const int*   ei = (const int*)d_in[1];
    const float* W  = (const float*)d_in[2];
    const float* b  = (const float*)d_in[3];
    const float* Wl = (const float*)d_in[4];
    const float* bl = (const float*)d_in[5];
    float* out = (float*)d_out;

    char* ws = (char*)d_ws;
    int*      cnt        = (int*)(ws + 0);         // 400000 B
    float*    dinv       = (float*)(ws + 400000);  // 400000 B
    int*      bucket_cnt = (int*)(ws + 800000);    // 3128 B
    int*      boff       = (int*)(ws + 803200);    // 3132 B
    int*      gcur       = (int*)(ws + 806400);    // 3128 B
    unsigned* ebuf       = (unsigned*)(ws + 1048576);   // 6.4 MB
    unsigned short* g16  = (unsigned short*)(ws + 7448576);  // 12.8 MB, 8B-aligned

    k_zero <<<(NN + 255) / 256, 256, 0, stream>>>(cnt, NN);
    k_count<<<(NE + 255) / 256, 256, 0, stream>>>(ei, cnt, NE);
    k_prep <<<391, 256, 0, stream>>>(cnt, dinv, bucket_cnt);
    k_bscan<<<1, 1024, 0, stream>>>(bucket_cnt, boff, gcur);
    k_binA <<<NTILE, 1024, 0, stream>>>(ei, gcur, ebuf, NE);
    k_gemm <<<2048, 256, 0, stream>>>(x, W, b, Wl, bl, dinv, g16, out, NN);
    k_gatherB<<<K, 512, 0, stream>>>(cnt, boff, ebuf, (const ushort4*)g16, dinv, out);
}

// Round 8
// 125.746 us; speedup vs baseline: 4.0546x; 1.4141x over previous
//
#include <hip/hip_runtime.h>

#define NN 100000
#define NE 1600000
#define DIM 64
#define K 782            // buckets of 128 nodes: b = dst >> 7
#define ABLK 8192        // edges per binning tile (binA)
#define NTILE 196        // ceil(NE / ABLK)
#define CBLK 4096        // edges per bcnt tile
#define NCTILE 391       // ceil(NE / CBLK)
#define GCAP 2600        // per-bucket edge capacity (mean 2046, 12 sigma)

__device__ __forceinline__ unsigned short f2bf(float f) {
    union { float f; unsigned u; } c; c.f = f;
    unsigned r = (c.u + 0x7FFFu + ((c.u >> 16) & 1u)) >> 16;   // RNE
    return (unsigned short)r;
}
__device__ __forceinline__ float bf2f(unsigned short h) {
    union { unsigned u; float f; } c; c.u = ((unsigned)h) << 16;
    return c.f;
}
__device__ __forceinline__ float lanebcast(float v, int k) {
    return __int_as_float(__builtin_amdgcn_readlane(__float_as_int(v), k));
}

// ---------------- per-bucket totals via LDS histogram ----------------

__global__ void k_zero(int* __restrict__ p, int n) {
    int i = blockIdx.x * blockDim.x + threadIdx.x;
    if (i < n) p[i] = 0;
}

__global__ __launch_bounds__(512) void k_bcnt(const int* __restrict__ ei,
                                              int* __restrict__ bucket_cnt, int E) {
    __shared__ int hist[K];
    const int tid = threadIdx.x;
    for (int j = tid; j < K; j += 512) hist[j] = 0;
    __syncthreads();
    const int e0 = blockIdx.x * CBLK;
#pragma unroll
    for (int i = 0; i < 8; ++i) {
        int e = e0 + i * 512 + tid;
        if (e < E) atomicAdd(&hist[ei[E + e] >> 7], 1);
    }
    __syncthreads();
    for (int j = tid; j < K; j += 512) {
        int h = hist[j];
        if (h > 0) atomicAdd(&bucket_cnt[j], h);
    }
}

// ---------------- scan bucket totals -> boff, init gcur ----------------

__global__ __launch_bounds__(1024) void k_bscan(const int* __restrict__ bucket_cnt,
                                                int* __restrict__ boff,
                                                int* __restrict__ gcur) {
    __shared__ int s[1024];
    int t = threadIdx.x;
    int v = (t < K) ? bucket_cnt[t] : 0;
    s[t] = v;
    __syncthreads();
    for (int off = 1; off < 1024; off <<= 1) {
        int a = (t >= off) ? s[t - off] : 0;
        __syncthreads();
        s[t] += a;
        __syncthreads();
    }
    if (t < K) {
        int ex = s[t] - v;
        boff[t] = ex;
        gcur[t] = ex;
        if (t == K - 1) boff[K] = s[t];   // == NE
    }
}

// ---------------- Phase A: bin edges by bucket, coalesced run writes ----------------

__global__ __launch_bounds__(1024) void k_binA(const int* __restrict__ ei,
                                               int* __restrict__ gcur,
                                               unsigned* __restrict__ ebuf, int E) {
    __shared__ int hist[1024];               // counts, then inclusive scan
    __shared__ int hoff[K];                  // run start within tile
    __shared__ int gbase[K];                 // claimed global base
    __shared__ int lcur[K];
    __shared__ unsigned sbufE[ABLK];         // packed (ldst<<17)|src, bucket-sorted
    __shared__ unsigned short sbufB[ABLK];   // bucket id per entry

    const int tid = threadIdx.x;
    const int e0 = blockIdx.x * ABLK;
    const int nval = min(ABLK, E - e0);

    hist[tid] = 0;
    __syncthreads();

    // pass 1: count (keep edges in registers)
    int pk_[8]; int b_[8]; int myN = 0;
#pragma unroll
    for (int i = 0; i < 8; ++i) {
        int e = e0 + i * 1024 + tid;
        if (e < E) {
            int dst = ei[E + e];
            int src = ei[e];
            int b = dst >> 7;
            pk_[myN]  = ((dst & 127) << 17) | src;
            b_[myN]   = b;
            ++myN;
            atomicAdd(&hist[b], 1);
        }
    }
    __syncthreads();

    int cntv = hist[tid];
    __syncthreads();
    for (int off = 1; off < 1024; off <<= 1) {
        int a = (tid >= off) ? hist[tid - off] : 0;
        __syncthreads();
        hist[tid] += a;
        __syncthreads();
    }
    if (tid < K) {
        int ho = hist[tid] - cntv;
        hoff[tid] = ho;
        lcur[tid] = ho;
        gbase[tid] = (cntv > 0) ? atomicAdd(&gcur[tid], cntv) : 0;
    }
    __syncthreads();

    // pass 2: place into LDS, bucket-sorted
    for (int j = 0; j < myN; ++j) {
        int pos = atomicAdd(&lcur[b_[j]], 1);
        sbufE[pos] = (unsigned)pk_[j];
        sbufB[pos] = (unsigned short)b_[j];
    }
    __syncthreads();

    // pass 3: coalesced run writes
    for (int j = tid; j < nval; j += 1024) {
        unsigned en = sbufE[j];
        int b = sbufB[j];
        ebuf[gbase[b] + (j - hoff[b])] = en;
    }
}

// ---------------- per-node dinv from bucket-sorted edges (LDS histogram) ----------------

__global__ __launch_bounds__(256) void k_dinvB(const int* __restrict__ boff,
                                               const unsigned* __restrict__ ebuf,
                                               float* __restrict__ dinv) {
    __shared__ int lcnt[128];
    const int tid = threadIdx.x;
    if (tid < 128) lcnt[tid] = 0;
    __syncthreads();
    const int base = boff[blockIdx.x];
    const int mB = boff[blockIdx.x + 1] - base;
    for (int i = tid; i < mB; i += 256) {
        atomicAdd(&lcnt[ebuf[base + i] >> 17], 1);
    }
    __syncthreads();
    if (tid < 128) {
        int nd = (blockIdx.x << 7) + tid;
        if (nd < NN) dinv[nd] = rsqrtf((float)(lcnt[tid] + 1));
    }
}

// ---------------- fused dense: g16 = bf16((xW)*dinv) ; out = xW_lin + b + b_lin + dinv*g

__global__ __launch_bounds__(256) void k_gemm(
    const float* __restrict__ x, const float* __restrict__ W,
    const float* __restrict__ b, const float* __restrict__ Wl,
    const float* __restrict__ bl, const float* __restrict__ dinv,
    unsigned short* __restrict__ g16, float* __restrict__ out, int n) {
    __shared__ float Ws[DIM * DIM];
    __shared__ float Wls[DIM * DIM];

    for (int i = threadIdx.x; i < DIM * DIM; i += 256) {
        Ws[i]  = W[i];
        Wls[i] = Wl[i];
    }
    __syncthreads();

    const int w = threadIdx.x >> 6;
    const int c = threadIdx.x & 63;
    const float bc = b[c] + bl[c];

    const int ntiles = n >> 4;   // NN = 16 * 6250, exact
    for (int tile = blockIdx.x; tile < ntiles; tile += gridDim.x) {
        const int row0 = (tile << 4) + (w << 2);
        const float* xp = x + (size_t)row0 * DIM + c;
        float xv0 = xp[0 * DIM], xv1 = xp[1 * DIM], xv2 = xp[2 * DIM], xv3 = xp[3 * DIM];

        float a0 = 0.f, a1 = 0.f, a2 = 0.f, a3 = 0.f;
        float l0 = 0.f, l1 = 0.f, l2 = 0.f, l3 = 0.f;
#pragma unroll
        for (int k = 0; k < DIM; ++k) {
            float wV = Ws[k * DIM + c];
            float wL = Wls[k * DIM + c];
            float x0 = lanebcast(xv0, k);
            float x1 = lanebcast(xv1, k);
            float x2 = lanebcast(xv2, k);
            float x3 = lanebcast(xv3, k);
            a0 += x0 * wV; l0 += x0 * wL;
            a1 += x1 * wV; l1 += x1 * wL;
            a2 += x2 * wV; l2 += x2 * wL;
            a3 += x3 * wV; l3 += x3 * wL;
        }
        float aj[4] = {a0, a1, a2, a3};
        float lj[4] = {l0, l1, l2, l3};
#pragma unroll
        for (int j = 0; j < 4; ++j) {
            int row = row0 + j;
            float dv = dinv[row];
            float gv = aj[j] * dv;
            g16[(size_t)row * DIM + c] = f2bf(gv);
            out[(size_t)row * DIM + c] = lj[j] + bc + dv * gv;
        }
    }
}

// ---------------- Phase B: LDS-local CSR + gather (512 thr = 8 waves/block) ----------------

__global__ __launch_bounds__(512) void k_gatherB(
    const int* __restrict__ boff, const unsigned* __restrict__ ebuf,
    const ushort4* __restrict__ g16, const float* __restrict__ dinv,
    float* __restrict__ out) {
    __shared__ int sS[128];
    __shared__ int lptr[128];
    __shared__ int lcur[128];
    __shared__ unsigned lsrc[GCAP];

    const int tid = threadIdx.x;
    const int lo = blockIdx.x << 7;
    const int base = boff[blockIdx.x];
    const int mB = boff[blockIdx.x + 1] - base;

    if (tid < 128) sS[tid] = 0;
    __syncthreads();

    // pass 1: LDS histogram of local dst
    for (int i = tid; i < mB; i += 512) {
        atomicAdd(&sS[ebuf[base + i] >> 17], 1);
    }
    __syncthreads();

    // exclusive scan of 128 counters
    int c = (tid < 128) ? sS[tid] : 0;
    __syncthreads();
    if (tid < 128) sS[tid] = c;
    __syncthreads();
    for (int off = 1; off < 128; off <<= 1) {
        int a = (tid < 128 && tid >= off) ? sS[tid - off] : 0;
        __syncthreads();
        if (tid < 128) sS[tid] += a;
        __syncthreads();
    }
    if (tid < 128) {
        int ex = sS[tid] - c;
        lptr[tid] = ex;
        lcur[tid] = ex;
    }
    __syncthreads();

    // pass 2: place (ebuf slice is L2-hot from pass 1)
    for (int i = tid; i < mB; i += 512) {
        unsigned en = ebuf[base + i];
        int ld = en >> 17;
        int pos = atomicAdd(&lcur[ld], 1);
        lsrc[pos] = en & 0x1FFFFu;
    }
    __syncthreads();

    const int w = tid >> 6;
    const int lane = tid & 63;
    const int grp = lane >> 4;
    const int sub = lane & 15;

    for (int node = w; node < 128; node += 8) {
        int gnode = lo + node;
        if (gnode >= NN) continue;
        int start = lptr[node];
        int m = lcur[node] - start;

        float ax = 0.f, ay = 0.f, az = 0.f, aw = 0.f;
        for (int b2 = 0; b2 < m; b2 += 64) {
            int rem = m - b2; if (rem > 64) rem = 64;
            int srcv = (lane < rem) ? (int)lsrc[start + b2 + lane] : 0;
            int nb4 = (rem + 3) >> 2;
            int bj = 0;
            for (; bj + 2 <= nb4; bj += 2) {
                int j0 = (bj << 2) + grp;
                int j1 = j0 + 4;
                int s0 = __shfl(srcv, j0);
                int s1 = __shfl(srcv, j1);
                ushort4 v0 = g16[s0 * 16 + sub];
                ushort4 v1 = g16[s1 * 16 + sub];
                if (j0 < rem) { ax += bf2f(v0.x); ay += bf2f(v0.y); az += bf2f(v0.z); aw += bf2f(v0.w); }
                if (j1 < rem) { ax += bf2f(v1.x); ay += bf2f(v1.y); az += bf2f(v1.z); aw += bf2f(v1.w); }
            }
            if (bj < nb4) {
                int j0 = (bj << 2) + grp;
                int s0 = __shfl(srcv, j0);
                ushort4 v0 = g16[s0 * 16 + sub];
                if (j0 < rem) { ax += bf2f(v0.x); ay += bf2f(v0.y); az += bf2f(v0.z); aw += bf2f(v0.w); }
            }
        }

        ax += __shfl_xor(ax, 16); ay += __shfl_xor(ay, 16);
        az += __shfl_xor(az, 16); aw += __shfl_xor(aw, 16);
        ax += __shfl_xor(ax, 32); ay += __shfl_xor(ay, 32);
        az += __shfl_xor(az, 32); aw += __shfl_xor(aw, 32);

        if (grp == 0) {
            float dv = dinv[gnode];
            float4* op = (float4*)(out + (size_t)gnode * DIM) + sub;
            float4 o = *op;
            o.x += dv * ax; o.y += dv * ay; o.z += dv * az; o.w += dv * aw;
            *op = o;
        }
    }
}

// ---------------- launch ----------------

extern "C" void kernel_launch(void* const* d_in, const int* in_sizes, int n_in,
                              void* d_out, int out_size, void* d_ws, size_t ws_size,
                              hipStream_t stream) {
    const float* x  = (const float*)d_in[0];
    const int*   ei = (const int*)d_in[1];
    const float* W  = (const float*)d_in[2];
    const float* b  = (const float*)d_in[3];
    const float* Wl = (const float*)d_in[4];
    const float* bl = (const float*)d_in[5];
    float* out = (float*)d_out;

    char* ws = (char*)d_ws;
    float*    dinv       = (float*)(ws + 0);       // 400000 B
    int*      bucket_cnt = (int*)(ws + 400000);    // 3128 B
    int*      boff       = (int*)(ws + 403200);    // 3132 B
    int*      gcur       = (int*)(ws + 406400);    // 3128 B
    unsigned* ebuf       = (unsigned*)(ws + 1048576);   // 6.4 MB
    unsigned short* g16  = (unsigned short*)(ws + 7448576);  // 12.8 MB, 8B-aligned

    k_zero <<<4, 256, 0, stream>>>(bucket_cnt, K);
    k_bcnt <<<NCTILE, 512, 0, stream>>>(ei, bucket_cnt, NE);
    k_bscan<<<1, 1024, 0, stream>>>(bucket_cnt, boff, gcur);
    k_binA <<<NTILE, 1024, 0, stream>>>(ei, gcur, ebuf, NE);
    k_dinvB<<<K, 256, 0, stream>>>(boff, ebuf, dinv);
    k_gemm <<<2048, 256, 0, stream>>>(x, W, b, Wl, bl, dinv, g16, out, NN);
    k_gatherB<<<K, 512, 0, stream>>>(boff, ebuf, (const ushort4*)g16, dinv, out);
}

// Round 9
// 99.437 us; speedup vs baseline: 5.1273x; 1.2646x over previous
//
#include <hip/hip_runtime.h>

#define NN 100000
#define NE 1600000
#define DIM 64
#define K 782            // buckets of 128 nodes: b = dst >> 7
#define ABLK 8192        // edges per binning tile (binA)
#define NTILE 196        // ceil(NE / ABLK)
#define CBLK 4096        // edges per bcnt tile
#define NCTILE 391       // ceil(NE / CBLK)
#define GCAP 2600        // per-bucket edge capacity (mean 2046, 12 sigma)

typedef __attribute__((ext_vector_type(8))) short bf16x8;
typedef __attribute__((ext_vector_type(4))) float f32x4;

__device__ __forceinline__ unsigned short f2bf(float f) {
    union { float f; unsigned u; } c; c.f = f;
    unsigned r = (c.u + 0x7FFFu + ((c.u >> 16) & 1u)) >> 16;   // RNE
    return (unsigned short)r;
}
__device__ __forceinline__ float bf2f(unsigned short h) {
    union { unsigned u; float f; } c; c.u = ((unsigned)h) << 16;
    return c.f;
}

// ---------------- per-bucket totals via LDS histogram ----------------

__global__ void k_zero(int* __restrict__ p, int n) {
    int i = blockIdx.x * blockDim.x + threadIdx.x;
    if (i < n) p[i] = 0;
}

__global__ __launch_bounds__(512) void k_bcnt(const int* __restrict__ ei,
                                              int* __restrict__ bucket_cnt, int E) {
    __shared__ int hist[K];
    const int tid = threadIdx.x;
    for (int j = tid; j < K; j += 512) hist[j] = 0;
    __syncthreads();
    const int e0 = blockIdx.x * CBLK;
#pragma unroll
    for (int i = 0; i < 8; ++i) {
        int e = e0 + i * 512 + tid;
        if (e < E) atomicAdd(&hist[ei[E + e] >> 7], 1);
    }
    __syncthreads();
    for (int j = tid; j < K; j += 512) {
        int h = hist[j];
        if (h > 0) atomicAdd(&bucket_cnt[j], h);
    }
}

// ---------------- scan bucket totals -> boff, init gcur ----------------

__global__ __launch_bounds__(1024) void k_bscan(const int* __restrict__ bucket_cnt,
                                                int* __restrict__ boff,
                                                int* __restrict__ gcur) {
    __shared__ int s[1024];
    int t = threadIdx.x;
    int v = (t < K) ? bucket_cnt[t] : 0;
    s[t] = v;
    __syncthreads();
    for (int off = 1; off < 1024; off <<= 1) {
        int a = (t >= off) ? s[t - off] : 0;
        __syncthreads();
        s[t] += a;
        __syncthreads();
    }
    if (t < K) {
        int ex = s[t] - v;
        boff[t] = ex;
        gcur[t] = ex;
        if (t == K - 1) boff[K] = s[t];   // == NE
    }
}

// ---------------- Phase A: bin edges by bucket, coalesced run writes ----------------

__global__ __launch_bounds__(1024) void k_binA(const int* __restrict__ ei,
                                               int* __restrict__ gcur,
                                               unsigned* __restrict__ ebuf, int E) {
    __shared__ int hist[1024];               // counts, then inclusive scan
    __shared__ int hoff[K];                  // run start within tile
    __shared__ int gbase[K];                 // claimed global base
    __shared__ int lcur[K];
    __shared__ unsigned sbufE[ABLK];         // packed (ldst<<17)|src, bucket-sorted
    __shared__ unsigned short sbufB[ABLK];   // bucket id per entry

    const int tid = threadIdx.x;
    const int e0 = blockIdx.x * ABLK;
    const int nval = min(ABLK, E - e0);

    hist[tid] = 0;
    __syncthreads();

    // pass 1: count (keep edges in registers)
    int pk_[8]; int b_[8]; int myN = 0;
#pragma unroll
    for (int i = 0; i < 8; ++i) {
        int e = e0 + i * 1024 + tid;
        if (e < E) {
            int dst = ei[E + e];
            int src = ei[e];
            int b = dst >> 7;
            pk_[myN]  = ((dst & 127) << 17) | src;
            b_[myN]   = b;
            ++myN;
            atomicAdd(&hist[b], 1);
        }
    }
    __syncthreads();

    int cntv = hist[tid];
    __syncthreads();
    for (int off = 1; off < 1024; off <<= 1) {
        int a = (tid >= off) ? hist[tid - off] : 0;
        __syncthreads();
        hist[tid] += a;
        __syncthreads();
    }
    if (tid < K) {
        int ho = hist[tid] - cntv;
        hoff[tid] = ho;
        lcur[tid] = ho;
        gbase[tid] = (cntv > 0) ? atomicAdd(&gcur[tid], cntv) : 0;
    }
    __syncthreads();

    // pass 2: place into LDS, bucket-sorted
    for (int j = 0; j < myN; ++j) {
        int pos = atomicAdd(&lcur[b_[j]], 1);
        sbufE[pos] = (unsigned)pk_[j];
        sbufB[pos] = (unsigned short)b_[j];
    }
    __syncthreads();

    // pass 3: coalesced run writes
    for (int j = tid; j < nval; j += 1024) {
        unsigned en = sbufE[j];
        int b = sbufB[j];
        ebuf[gbase[b] + (j - hoff[b])] = en;
    }
}

// ---------------- per-node dinv from bucket-sorted edges (LDS histogram) ----------------

__global__ __launch_bounds__(256) void k_dinvB(const int* __restrict__ boff,
                                               const unsigned* __restrict__ ebuf,
                                               float* __restrict__ dinv) {
    __shared__ int lcnt[128];
    const int tid = threadIdx.x;
    if (tid < 128) lcnt[tid] = 0;
    __syncthreads();
    const int base = boff[blockIdx.x];
    const int mB = boff[blockIdx.x + 1] - base;
    for (int i = tid; i < mB; i += 256) {
        atomicAdd(&lcnt[ebuf[base + i] >> 17], 1);
    }
    __syncthreads();
    if (tid < 128) {
        int nd = (blockIdx.x << 7) + tid;
        if (nd < NN) dinv[nd] = rsqrtf((float)(lcnt[tid] + 1));
    }
}

// ---------------- MFMA dense: [h|lin] = bf16(x) @ bf16([W|Wl]) ----------------
// Block = 64 rows x 4 waves; wave = 16 rows x 128 cols (8 col-tiles x 2 MFMA, K=64).
// A frag: row = lane&15, k = 8*(lane>>4)+j.  B frag: col = lane&15, same k walk.
// C/D: col = lane&15, row = 4*(lane>>4)+reg (m89-verified).

__global__ __launch_bounds__(256) void k_gemm(
    const float* __restrict__ x, const float* __restrict__ W,
    const float* __restrict__ b, const float* __restrict__ Wl,
    const float* __restrict__ bl, const float* __restrict__ dinv,
    unsigned short* __restrict__ g16, float* __restrict__ out) {
    __shared__ unsigned short WcT[128][72];   // [col][k] bf16, k padded 64->72

    const int tid = threadIdx.x;
    {   // stage [W | Wl]^T into LDS as bf16 (W is [k][c] row-major)
        const float4* W4  = (const float4*)W;
        const float4* Wl4 = (const float4*)Wl;
        for (int i = tid; i < 1024; i += 256) {   // 4096 floats / 4
            int k  = i >> 4;
            int c0 = (i & 15) << 2;
            float4 wv = W4[i];
            float4 lv = Wl4[i];
            WcT[c0 + 0][k] = f2bf(wv.x); WcT[c0 + 1][k] = f2bf(wv.y);
            WcT[c0 + 2][k] = f2bf(wv.z); WcT[c0 + 3][k] = f2bf(wv.w);
            WcT[64 + c0 + 0][k] = f2bf(lv.x); WcT[64 + c0 + 1][k] = f2bf(lv.y);
            WcT[64 + c0 + 2][k] = f2bf(lv.z); WcT[64 + c0 + 3][k] = f2bf(lv.w);
        }
    }
    __syncthreads();

    const int wv_  = tid >> 6;
    const int lane = tid & 63;
    const int lr   = lane & 15;
    const int lkb  = (lane >> 4) << 3;        // k base: 0,8,16,24

    const int row0 = blockIdx.x * 64 + wv_ * 16;
    if (row0 >= NN) return;

    // A fragments (2 K-chunks of 32)
    int arow = row0 + lr;
    int arc  = arow < NN ? arow : NN - 1;
    const float* xp = x + (size_t)arc * DIM + lkb;
    float4 p0 = *(const float4*)(xp);
    float4 p1 = *(const float4*)(xp + 4);
    float4 p2 = *(const float4*)(xp + 32);
    float4 p3 = *(const float4*)(xp + 36);
    bf16x8 a0 = {(short)f2bf(p0.x), (short)f2bf(p0.y), (short)f2bf(p0.z), (short)f2bf(p0.w),
                 (short)f2bf(p1.x), (short)f2bf(p1.y), (short)f2bf(p1.z), (short)f2bf(p1.w)};
    bf16x8 a1 = {(short)f2bf(p2.x), (short)f2bf(p2.y), (short)f2bf(p2.z), (short)f2bf(p2.w),
                 (short)f2bf(p3.x), (short)f2bf(p3.y), (short)f2bf(p3.z), (short)f2bf(p3.w)};

    f32x4 acc[8];
#pragma unroll
    for (int ct = 0; ct < 8; ++ct) acc[ct] = (f32x4){0.f, 0.f, 0.f, 0.f};

#pragma unroll
    for (int ct = 0; ct < 8; ++ct) {
        bf16x8 b0 = *(const bf16x8*)&WcT[ct * 16 + lr][lkb];
        bf16x8 b1 = *(const bf16x8*)&WcT[ct * 16 + lr][32 + lkb];
        acc[ct] = __builtin_amdgcn_mfma_f32_16x16x32_bf16(a0, b0, acc[ct], 0, 0, 0);
        acc[ct] = __builtin_amdgcn_mfma_f32_16x16x32_bf16(a1, b1, acc[ct], 0, 0, 0);
    }

    // epilogue
    float bcv[4];
#pragma unroll
    for (int ct = 0; ct < 4; ++ct) {
        int oc = ct * 16 + lr;
        bcv[ct] = b[oc] + bl[oc];
    }
    const int rbase = row0 + ((lane >> 4) << 2);
#pragma unroll
    for (int i = 0; i < 4; ++i) {
        int r = rbase + i;
        if (r >= NN) continue;
        float dv = dinv[r];
#pragma unroll
        for (int ct = 0; ct < 4; ++ct) {
            int oc = ct * 16 + lr;
            float accW = acc[ct][i];
            float accL = acc[ct + 4][i];
            float gvv = accW * dv;                        // dinv[src] folded into msg
            g16[(size_t)r * DIM + oc] = f2bf(gvv);
            out[(size_t)r * DIM + oc] = accL + bcv[ct] + dv * gvv;
        }
    }
}

// ---------------- Phase B: LDS-local CSR + gather (512 thr = 8 waves/block) ----------------

__global__ __launch_bounds__(512) void k_gatherB(
    const int* __restrict__ boff, const unsigned* __restrict__ ebuf,
    const ushort4* __restrict__ g16, const float* __restrict__ dinv,
    float* __restrict__ out) {
    __shared__ int sS[128];
    __shared__ int lptr[128];
    __shared__ int lcur[128];
    __shared__ unsigned lsrc[GCAP];

    const int tid = threadIdx.x;
    const int lo = blockIdx.x << 7;
    const int base = boff[blockIdx.x];
    const int mB = boff[blockIdx.x + 1] - base;

    if (tid < 128) sS[tid] = 0;
    __syncthreads();

    // pass 1: LDS histogram of local dst
    for (int i = tid; i < mB; i += 512) {
        atomicAdd(&sS[ebuf[base + i] >> 17], 1);
    }
    __syncthreads();

    // exclusive scan of 128 counters
    int c = (tid < 128) ? sS[tid] : 0;
    __syncthreads();
    if (tid < 128) sS[tid] = c;
    __syncthreads();
    for (int off = 1; off < 128; off <<= 1) {
        int a = (tid < 128 && tid >= off) ? sS[tid - off] : 0;
        __syncthreads();
        if (tid < 128) sS[tid] += a;
        __syncthreads();
    }
    if (tid < 128) {
        int ex = sS[tid] - c;
        lptr[tid] = ex;
        lcur[tid] = ex;
    }
    __syncthreads();

    // pass 2: place (ebuf slice is L2-hot from pass 1)
    for (int i = tid; i < mB; i += 512) {
        unsigned en = ebuf[base + i];
        int ld = en >> 17;
        int pos = atomicAdd(&lcur[ld], 1);
        lsrc[pos] = en & 0x1FFFFu;
    }
    __syncthreads();

    const int w = tid >> 6;
    const int lane = tid & 63;
    const int grp = lane >> 4;
    const int sub = lane & 15;

    for (int node = w; node < 128; node += 8) {
        int gnode = lo + node;
        if (gnode >= NN) continue;
        int start = lptr[node];
        int m = lcur[node] - start;

        float ax = 0.f, ay = 0.f, az = 0.f, aw = 0.f;
        for (int b2 = 0; b2 < m; b2 += 64) {
            int rem = m - b2; if (rem > 64) rem = 64;
            int srcv = (lane < rem) ? (int)lsrc[start + b2 + lane] : 0;
            int nb4 = (rem + 3) >> 2;
            int bj = 0;
            for (; bj + 2 <= nb4; bj += 2) {
                int j0 = (bj << 2) + grp;
                int j1 = j0 + 4;
                int s0 = __shfl(srcv, j0);
                int s1 = __shfl(srcv, j1);
                ushort4 v0 = g16[s0 * 16 + sub];
                ushort4 v1 = g16[s1 * 16 + sub];
                if (j0 < rem) { ax += bf2f(v0.x); ay += bf2f(v0.y); az += bf2f(v0.z); aw += bf2f(v0.w); }
                if (j1 < rem) { ax += bf2f(v1.x); ay += bf2f(v1.y); az += bf2f(v1.z); aw += bf2f(v1.w); }
            }
            if (bj < nb4) {
                int j0 = (bj << 2) + grp;
                int s0 = __shfl(srcv, j0);
                ushort4 v0 = g16[s0 * 16 + sub];
                if (j0 < rem) { ax += bf2f(v0.x); ay += bf2f(v0.y); az += bf2f(v0.z); aw += bf2f(v0.w); }
            }
        }

        ax += __shfl_xor(ax, 16); ay += __shfl_xor(ay, 16);
        az += __shfl_xor(az, 16); aw += __shfl_xor(aw, 16);
        ax += __shfl_xor(ax, 32); ay += __shfl_xor(ay, 32);
        az += __shfl_xor(az, 32); aw += __shfl_xor(aw, 32);

        if (grp == 0) {
            float dv = dinv[gnode];
            float4* op = (float4*)(out + (size_t)gnode * DIM) + sub;
            float4 o = *op;
            o.x += dv * ax; o.y += dv * ay; o.z += dv * az; o.w += dv * aw;
            *op = o;
        }
    }
}

// ---------------- launch ----------------

extern "C" void kernel_launch(void* const* d_in, const int* in_sizes, int n_in,
                              void* d_out, int out_size, void* d_ws, size_t ws_size,
                              hipStream_t stream) {
    const float* x  = (const float*)d_in[0];
    const int*   ei = (const int*)d_in[1];
    const float* W  = (const float*)d_in[2];
    const float* b  = (const float*)d_in[3];
    const float* Wl = (const float*)d_in[4];
    const float* bl = (const float*)d_in[5];
    float* out = (float*)d_out;

    char* ws = (char*)d_ws;
    float*    dinv       = (float*)(ws + 0);       // 400000 B
    int*      bucket_cnt = (int*)(ws + 400000);    // 3128 B
    int*      boff       = (int*)(ws + 403200);    // 3132 B
    int*      gcur       = (int*)(ws + 406400);    // 3128 B
    unsigned* ebuf       = (unsigned*)(ws + 1048576);   // 6.4 MB
    unsigned short* g16  = (unsigned short*)(ws + 7448576);  // 12.8 MB, 8B-aligned

    k_zero <<<4, 256, 0, stream>>>(bucket_cnt, K);
    k_bcnt <<<NCTILE, 512, 0, stream>>>(ei, bucket_cnt, NE);
    k_bscan<<<1, 1024, 0, stream>>>(bucket_cnt, boff, gcur);
    k_binA <<<NTILE, 1024, 0, stream>>>(ei, gcur, ebuf, NE);
    k_dinvB<<<K, 256, 0, stream>>>(boff, ebuf, dinv);
    k_gemm <<<1563, 256, 0, stream>>>(x, W, b, Wl, bl, dinv, g16, out);
    k_gatherB<<<K, 512, 0, stream>>>(boff, ebuf, (const ushort4*)g16, dinv, out);
}